// Round 5
// baseline (16941.602 us; speedup 1.0000x reference)
//
#include <hip/hip_runtime.h>

typedef unsigned short u16;
typedef __attribute__((ext_vector_type(4))) float f32x4;
typedef __attribute__((ext_vector_type(2))) float f32x2;
typedef __attribute__((ext_vector_type(8))) short short8;

#define B_ 32
#define P_ 196
#define T_ 64
#define V_ 32000
#define SLABF 17408   // 64KB data + 4KB guard pad, in floats

// Cross-block producers: relaxed agent-scope stores (land at MALL, coherent).
// Consumers: inline-asm sc0 loads (bypass L1, FILL L2 from MALL) on t-indexed
// buffers -> every slab address is written (MALL) before any read this launch,
// and the dispatch acquire invalidates L2 across launches. Ordering for flags
// comes from __syncthreads() (vmcnt(0) drain before s_barrier).
#define AT_LOAD(p)     __hip_atomic_load((p), __ATOMIC_RELAXED, __HIP_MEMORY_SCOPE_AGENT)
#define AT_STORE(p,v)  __hip_atomic_store((p), (v), __ATOMIC_RELAXED, __HIP_MEMORY_SCOPE_AGENT)

__device__ __forceinline__ u16 f2bf(float x){
  unsigned int u = __float_as_uint(x);
  u += 0x7FFFu + ((u >> 16) & 1u);
  return (u16)(u >> 16);
}
__device__ __forceinline__ float bf2f(u16 x){
  return __uint_as_float(((unsigned int)x) << 16);
}
__device__ __forceinline__ float sigf(float x){ return 1.0f/(1.0f + __expf(-x)); }
__device__ __forceinline__ float tanhfast(float x){
  float e = __expf(-2.0f*fabsf(x));
  float t = (1.0f - e)/(1.0f + e);
  return x >= 0.0f ? t : -t;
}

// single sc0 (L2-coherent) scalar load
__device__ __forceinline__ float ld_sc0(const float* p){
  float r;
  asm volatile("global_load_dword %0, %1, off sc0\n\ts_waitcnt vmcnt(0)"
               : "=&v"(r) : "v"(p) : "memory");
  return r;
}

// 16 x dwordx4 sc0 loads (two buffers, two 16-float groups each at +0/+1024B)
__device__ __forceinline__ void ld16_sc0(const float* pa, const float* pb,
    f32x4& a0,f32x4& a1,f32x4& a2,f32x4& a3,f32x4& a4,f32x4& a5,f32x4& a6,f32x4& a7,
    f32x4& b0,f32x4& b1,f32x4& b2,f32x4& b3,f32x4& b4,f32x4& b5,f32x4& b6,f32x4& b7){
  asm volatile(
    "global_load_dwordx4 %0, %16, off sc0\n\t"
    "global_load_dwordx4 %1, %16, off offset:16 sc0\n\t"
    "global_load_dwordx4 %2, %16, off offset:32 sc0\n\t"
    "global_load_dwordx4 %3, %16, off offset:48 sc0\n\t"
    "global_load_dwordx4 %4, %16, off offset:1024 sc0\n\t"
    "global_load_dwordx4 %5, %16, off offset:1040 sc0\n\t"
    "global_load_dwordx4 %6, %16, off offset:1056 sc0\n\t"
    "global_load_dwordx4 %7, %16, off offset:1072 sc0\n\t"
    "global_load_dwordx4 %8, %17, off sc0\n\t"
    "global_load_dwordx4 %9, %17, off offset:16 sc0\n\t"
    "global_load_dwordx4 %10, %17, off offset:32 sc0\n\t"
    "global_load_dwordx4 %11, %17, off offset:48 sc0\n\t"
    "global_load_dwordx4 %12, %17, off offset:1024 sc0\n\t"
    "global_load_dwordx4 %13, %17, off offset:1040 sc0\n\t"
    "global_load_dwordx4 %14, %17, off offset:1056 sc0\n\t"
    "global_load_dwordx4 %15, %17, off offset:1072 sc0\n\t"
    "s_waitcnt vmcnt(0)"
    : "=&v"(a0),"=&v"(a1),"=&v"(a2),"=&v"(a3),"=&v"(a4),"=&v"(a5),"=&v"(a6),"=&v"(a7),
      "=&v"(b0),"=&v"(b1),"=&v"(b2),"=&v"(b3),"=&v"(b4),"=&v"(b5),"=&v"(b6),"=&v"(b7)
    : "v"(pa), "v"(pb)
    : "memory");
}

// ---------- setup kernels ----------

__global__ __launch_bounds__(256) void k_cvt_bf16(const float* __restrict__ s,
                                                  u16* __restrict__ d, int n8){
  int i = blockIdx.x*256 + threadIdx.x;
  if (i >= n8) return;
  const f32x4* sp = (const f32x4*)(s + (size_t)i*8);
  f32x4 a = sp[0], b = sp[1];
  short8 v;
#pragma unroll
  for (int j=0;j<4;++j){ v[j] = (short)f2bf(a[j]); v[4+j] = (short)f2bf(b[j]); }
  *(short8*)(d + (size_t)i*8) = v;
}

__global__ __launch_bounds__(256) void k_wencT(const float* __restrict__ W, u16* __restrict__ WT){
  int tid = threadIdx.x;
  int kc = tid & 63, a = blockIdx.x*4 + (tid >> 6);
  short8 v;
#pragma unroll
  for (int j=0;j<8;++j) v[j] = (short)f2bf(W[(kc*8+j)*512 + a]);
  *(short8*)(WT + a*512 + kc*8) = v;
}

__global__ __launch_bounds__(256) void k_mean(const float* __restrict__ enc, float* __restrict__ mean){
  int b = blockIdx.x, tid = threadIdx.x;
  f32x2 acc; acc.x = 0.f; acc.y = 0.f;
  for (int p=0;p<P_;++p){
    f32x2 v = *(const f32x2*)(enc + ((size_t)(b*P_+p))*512 + tid*2);
    acc.x += v.x; acc.y += v.y;
  }
  acc.x *= (1.0f/196.0f); acc.y *= (1.0f/196.0f);
  *(f32x2*)(mean + b*512 + tid*2) = acc;
}

__global__ __launch_bounds__(256) void k_init_state(const float* __restrict__ mean,
    const float* __restrict__ Wh, const float* __restrict__ bh,
    const float* __restrict__ Wc, const float* __restrict__ bc,
    float* __restrict__ h0, float* __restrict__ h1,
    float* __restrict__ c0, float* __restrict__ c1){
  int bid = blockIdx.x;
  int which = bid >> 7, r = (bid >> 2) & 31, jg = bid & 3;
  const float* W = which ? Wc : Wh;
  const float* bb = which ? bc : bh;
  __shared__ float m[512];
  for (int i=threadIdx.x; i<512; i+=256) m[i] = mean[r*512 + i];
  __syncthreads();
  int j = jg*256 + threadIdx.x;
  float acc = bb[j];
  for (int e=0;e<512;++e) acc += m[e]*W[e*1024 + j];
  int l = r >> 4;
  int bb2 = ((r & 15) << 1) | (j >> 9);
  int hh = j & 511;
  float* dst = which ? (l ? c1 : c0) : (l ? h1 : h0);
  dst[bb2*512 + hh] = acc;
}

// fused LSTM weights: W0f[2048][1536] = [Wih0 | Whh0], W1f[2048][1024] = [Wih1 | Whh1]
__global__ __launch_bounds__(256) void k_fuse_w(const float* __restrict__ Wih0,
    const float* __restrict__ Whh0, const float* __restrict__ Wih1,
    const float* __restrict__ Whh1, float* __restrict__ W0f, float* __restrict__ W1f){
  int r = blockIdx.x, tid = threadIdx.x;
  if (r < 2048){
    for (int k=tid; k<1536; k+=256)
      W0f[(size_t)r*1536+k] = (k<1024) ? Wih0[(size_t)r*1024+k] : Whh0[(size_t)r*512 + (k-1024)];
  } else {
    int r1 = r - 2048;
    for (int k=tid; k<1024; k+=256)
      W1f[(size_t)r1*1024+k] = (k<512) ? Wih1[(size_t)r1*512+k] : Whh1[(size_t)r1*512 + (k-512)];
  }
}

// ---------- bf16 GEMM (LDS pad 40 u16): C[M][N] = A[M][512]*Bm[N][512]^T + bias ----------
#define LDAP 40
__global__ __launch_bounds__(256) void k_gemm_bf16(
    const u16* __restrict__ A, const u16* __restrict__ Bm,
    const float* __restrict__ bias, float* __restrict__ C, int N){
  __shared__ __align__(16) u16 As[128*LDAP];
  __shared__ __align__(16) u16 Bs[128*LDAP];
  int tid = threadIdx.x, l = tid & 63, w = tid >> 6;
  int m0 = blockIdx.x * 128, n0 = blockIdx.y * 128;
  int wm = w >> 1, wn = w & 1;
  f32x4 acc[4][4];
#pragma unroll
  for (int a=0;a<4;++a)
#pragma unroll
    for (int b=0;b<4;++b) acc[a][b] = (f32x4)0.0f;
  int srow = tid >> 2, schunk = tid & 3;
  const u16* gA = A + (size_t)(m0 + srow)*512 + schunk*8;
  const u16* gB = Bm + (size_t)(n0 + srow)*512 + schunk*8;
  int lr = l & 15, lk = (l >> 4) * 8;
  for (int k0 = 0; k0 < 512; k0 += 32){
    short8 va0 = *(const short8*)(gA + k0);
    short8 va1 = *(const short8*)(gA + (size_t)64*512 + k0);
    short8 vb0 = *(const short8*)(gB + k0);
    short8 vb1 = *(const short8*)(gB + (size_t)64*512 + k0);
    __syncthreads();
    *(short8*)(As + srow*LDAP + schunk*8) = va0;
    *(short8*)(As + (64+srow)*LDAP + schunk*8) = va1;
    *(short8*)(Bs + srow*LDAP + schunk*8) = vb0;
    *(short8*)(Bs + (64+srow)*LDAP + schunk*8) = vb1;
    __syncthreads();
    short8 af[4], bfv[4];
#pragma unroll
    for (int mt=0; mt<4; ++mt) af[mt]  = *(const short8*)(As + (wm*64 + mt*16 + lr)*LDAP + lk);
#pragma unroll
    for (int nt=0; nt<4; ++nt) bfv[nt] = *(const short8*)(Bs + (wn*64 + nt*16 + lr)*LDAP + lk);
#pragma unroll
    for (int mt=0; mt<4; ++mt)
#pragma unroll
      for (int nt=0; nt<4; ++nt)
        acc[mt][nt] = __builtin_amdgcn_mfma_f32_16x16x32_bf16(af[mt], bfv[nt], acc[mt][nt], 0, 0, 0);
  }
#pragma unroll
  for (int mt=0; mt<4; ++mt){
    int row = m0 + wm*64 + mt*16 + ((l >> 4) << 2);
#pragma unroll
    for (int nt=0; nt<4; ++nt){
      int col = n0 + wn*64 + nt*16 + (l & 15);
      float bv = bias[col];
#pragma unroll
      for (int j=0;j<4;++j)
        C[(size_t)(row + j)*N + col] = acc[mt][nt][j] + bv;
    }
  }
}

// ---------- persistent recurrence kernel ----------

struct RA {
  const float* enc; const int* caps; const float* embW;
  const float* Wdec; const float* bdec; const float* Wfull; const float* bfull;
  const u16* encattBF; const float* W0f; const float* W1f;
  const float* bih0; const float* bhh0; const float* bih1; const float* bhh1;
  float* h0g; float* h1g; float* att2g; float* ctxg;    // t-indexed slabs
  const float* c0init; const float* c1init;
  u16* h1_all; int* slots; int* go;
};

__device__ __forceinline__ void gbar(int* slots, int* go, int gen){
  __syncthreads();
  if (blockIdx.x == 0){
    int tid = threadIdx.x;
    if (tid >= 1 && tid < 256){
      while (AT_LOAD(&slots[tid]) < gen) __builtin_amdgcn_s_sleep(1);
    }
    __syncthreads();
    if (tid == 0) AT_STORE(go, gen);
  } else {
    if (threadIdx.x == 0){
      AT_STORE(&slots[blockIdx.x], gen);
      while (AT_LOAD(go) < gen) __builtin_amdgcn_s_sleep(1);
    }
    __syncthreads();
  }
}

__global__ __launch_bounds__(512, 1) void k_recur(RA a){
  int bid = blockIdx.x, tid = threadIdx.x;
  int lane = tid & 63, wv = tid >> 6;
  // LDS: weights (swizzled) + scratch
  __shared__ __align__(16) float w0s[12288];  // 48KB: [(r*6+g)*4+q][ksg][4]
  __shared__ __align__(16) float w1s[8192];   // 32KB: [(r*4+g)*4+q][ksg][4]
  __shared__ float red[1280];
  __shared__ float gsum[256];
  __shared__ float c0s[64], c1s[64];
  __shared__ float SinvS;

  // XCD-friendly logical mapping (perf heuristic only)
  int ab = (bid & 7)*4 + (bid >> 6);   // batch 0..31
  int as = (bid >> 3) & 7;             // col-slice 0..7
  int c0col = as*64;
  int b31 = tid >> 4, ksg = tid & 15, kq4 = ksg*4;

  // load this block's weight rows into LDS (swizzled layout), once
  // local row index ri in 0..7: gate = ri&3, ci = ri>>2; global row = gate*512 + bid*2 + ci
  for (int idx = tid; idx < 12288; idx += 512){
    int e = idx & 3, ks_ = (idx >> 2) & 15, q = (idx >> 6) & 3, rg = idx >> 8; // rg = ri*6+g
    int ri = rg / 6, g = rg - ri*6;
    int grow = (ri & 3)*512 + bid*2 + (ri >> 2);
    int k = g*256 + ks_*16 + q*4 + e;
    w0s[idx] = a.W0f[(size_t)grow*1536 + k];
  }
  for (int idx = tid; idx < 8192; idx += 512){
    int e = idx & 3, ks_ = (idx >> 2) & 15, q = (idx >> 6) & 3, rg = idx >> 8; // rg = ri*4+g
    int ri = rg >> 2, g = rg & 3;
    int grow = (ri & 3)*512 + bid*2 + (ri >> 2);
    int k = g*256 + ks_*16 + q*4 + e;
    w1s[idx] = a.W1f[(size_t)grow*1024 + k];
  }
  if (tid < 64){
    int ci = tid >> 5, b = tid & 31, cell = bid*2 + ci;
    c0s[ci*32+b] = a.c0init[b*512 + cell];
    c1s[ci*32+b] = a.c1init[b*512 + cell];
  }
  __syncthreads();

  for (int t = 0; t < T_; ++t){
    const float* h1_rd  = a.h1g  + (size_t)t*SLABF;        // h1(t-1); slot0 = init
    const float* h0_rd  = a.h0g  + (size_t)t*SLABF;
    float*       h0_wr  = a.h0g  + (size_t)(t+1)*SLABF;
    float*       h1_wr  = a.h1g  + (size_t)(t+1)*SLABF;
    float*       at_wr  = a.att2g + (size_t)t*SLABF;
    const float* at_rd  = at_wr;
    float*       cx_wr  = a.ctxg + (size_t)t*SLABF;
    const float* cx_rd  = cx_wr;
    int genb = t*4;

    // ---- P1: att2 cols [c0col, c0col+64) for batch ab ----
    {
      float* h1s = red; float* gp = red + 512;
      h1s[tid] = ld_sc0(&h1_rd[ab*512 + tid]);
      __syncthreads();
      int c = tid & 63, ksx = tid >> 6;
      float accp = 0.f;
      const float* wpd = a.Wdec + (size_t)(ksx*64)*512 + c0col + c;
#pragma unroll 8
      for (int i=0;i<64;++i) accp = fmaf(h1s[ksx*64+i], wpd[(size_t)i*512], accp);
      gp[ksx*64+c] = accp;
      __syncthreads();
      if (tid < 64){
        float s = a.bdec[c0col+tid];
#pragma unroll
        for (int k=0;k<8;++k) s += gp[k*64+tid];
        AT_STORE(&at_wr[ab*512 + c0col + tid], s);
      }
    }
    gbar(a.slots, a.go, genb+1);

    // ---- P23: logits+softmax (redundant per batch group) + ctx cols ----
    {
      float* att2s = red; float* gp3 = red + 512; float* alph = red + 1024;
      att2s[tid] = ld_sc0(&at_rd[ab*512 + tid]);
      __syncthreads();
      float a2[8], wf[8];
#pragma unroll
      for (int j=0;j<8;++j){ a2[j] = att2s[lane*8+j]; wf[j] = a.Wfull[lane*8+j]; }
      float bf0 = a.bfull[0];
      int np = (wv < 4) ? 25 : 24;
      for (int i=0;i<np;++i){
        int p = wv + i*8;
        const u16* ep = a.encattBF + ((size_t)(ab*P_ + p))*512 + lane*8;
        short8 ev = *(const short8*)ep;
        float s = 0.f;
#pragma unroll
        for (int j=0;j<8;++j)
          s += fmaxf(bf2f((u16)ev[j]) + a2[j], 0.f) * wf[j];
#pragma unroll
        for (int o=32;o>=1;o>>=1) s += __shfl_xor(s, o);
        if (lane == 0) alph[p] = __expf(s + bf0);
      }
      __syncthreads();
      if (wv == 0){
        float v = 0.f;
#pragma unroll
        for (int i=0;i<4;++i){ int p = lane + 64*i; if (p < P_) v += alph[p]; }
#pragma unroll
        for (int o=32;o>=1;o>>=1) v += __shfl_xor(v, o);
        if (lane == 0) SinvS = 1.0f / v;
      }
      int c = tid & 63, pk = tid >> 6;
      float accp = 0.f;
      for (int i=0;i<25;++i){
        int p = pk + 8*i;
        if (p < P_) accp = fmaf(alph[p], a.enc[((size_t)(ab*P_ + p))*512 + c0col + c], accp);
      }
      gp3[pk*64+c] = accp;
      __syncthreads();
      if (tid < 64){
        float s = 0.f;
#pragma unroll
        for (int k=0;k<8;++k) s += gp3[k*64+tid];
        AT_STORE(&cx_wr[ab*512 + c0col + tid], s * SinvS);
      }
    }
    gbar(a.slots, a.go, genb+2);

    // ---- P4: LSTM layer 0 (block owns cells bid*2, bid*2+1) ----
    {
      int cap = a.caps[b31*T_ + t];
      f32x4 xv[6][4];
      const float* ep = a.embW + (size_t)cap*512 + kq4*4;
#pragma unroll
      for (int q=0;q<4;++q) xv[0][q] = *(const f32x4*)(ep + q*4);
#pragma unroll
      for (int q=0;q<4;++q) xv[1][q] = *(const f32x4*)(ep + 256 + q*4);
      const float* pc = cx_rd + b31*512 + kq4*4;
      const float* ph = h0_rd + b31*512 + kq4*4;
      ld16_sc0(pc, ph,
               xv[2][0],xv[2][1],xv[2][2],xv[2][3], xv[3][0],xv[3][1],xv[3][2],xv[3][3],
               xv[4][0],xv[4][1],xv[4][2],xv[4][3], xv[5][0],xv[5][1],xv[5][2],xv[5][3]);
      float acc8[8];
#pragma unroll
      for (int r=0;r<8;++r) acc8[r] = 0.f;
#pragma unroll
      for (int g=0; g<6; ++g)
#pragma unroll
        for (int q=0; q<4; ++q){
          f32x4 xq = xv[g][q];
          const float* wb = w0s + (g*4+q)*64 + kq4;
#pragma unroll
          for (int r=0; r<8; ++r){
            f32x4 w4 = *(const f32x4*)(wb + r*1536);
            acc8[r] = fmaf(xq.x,w4.x, fmaf(xq.y,w4.y, fmaf(xq.z,w4.z, fmaf(xq.w,w4.w, acc8[r]))));
          }
        }
#pragma unroll
      for (int r=0;r<8;++r){
        float v = acc8[r];
        v += __shfl_xor(v,1); v += __shfl_xor(v,2); v += __shfl_xor(v,4); v += __shfl_xor(v,8);
        if (ksg == 0) gsum[r*32 + b31] = v;
      }
      __syncthreads();
      if (tid < 64){
        int ci = tid >> 5, bb = tid & 31, cell = bid*2 + ci;
        float G[4];
#pragma unroll
        for (int g=0;g<4;++g)
          G[g] = gsum[(ci*4+g)*32 + bb] + a.bih0[g*512+cell] + a.bhh0[g*512+cell];
        float cp = c0s[ci*32+bb];
        float cn = sigf(G[1])*cp + sigf(G[0])*tanhfast(G[2]);
        float hn = sigf(G[3])*tanhfast(cn);
        c0s[ci*32+bb] = cn;
        AT_STORE(&h0_wr[bb*512 + cell], hn);
      }
      __syncthreads();
    }
    gbar(a.slots, a.go, genb+3);

    // ---- P5: LSTM layer 1 ----
    {
      f32x4 xv[4][4];
      const float* pa_ = h0_wr + b31*512 + kq4*4;
      const float* pb_ = h1_rd + b31*512 + kq4*4;
      ld16_sc0(pa_, pb_,
               xv[0][0],xv[0][1],xv[0][2],xv[0][3], xv[1][0],xv[1][1],xv[1][2],xv[1][3],
               xv[2][0],xv[2][1],xv[2][2],xv[2][3], xv[3][0],xv[3][1],xv[3][2],xv[3][3]);
      float acc8[8];
#pragma unroll
      for (int r=0;r<8;++r) acc8[r] = 0.f;
#pragma unroll
      for (int g=0; g<4; ++g)
#pragma unroll
        for (int q=0; q<4; ++q){
          f32x4 xq = xv[g][q];
          const float* wb = w1s + (g*4+q)*64 + kq4;
#pragma unroll
          for (int r=0; r<8; ++r){
            f32x4 w4 = *(const f32x4*)(wb + r*1024);
            acc8[r] = fmaf(xq.x,w4.x, fmaf(xq.y,w4.y, fmaf(xq.z,w4.z, fmaf(xq.w,w4.w, acc8[r]))));
          }
        }
#pragma unroll
      for (int r=0;r<8;++r){
        float v = acc8[r];
        v += __shfl_xor(v,1); v += __shfl_xor(v,2); v += __shfl_xor(v,4); v += __shfl_xor(v,8);
        if (ksg == 0) gsum[r*32 + b31] = v;
      }
      __syncthreads();
      if (tid < 64){
        int ci = tid >> 5, bb = tid & 31, cell = bid*2 + ci;
        float G[4];
#pragma unroll
        for (int g=0;g<4;++g)
          G[g] = gsum[(ci*4+g)*32 + bb] + a.bih1[g*512+cell] + a.bhh1[g*512+cell];
        float cp = c1s[ci*32+bb];
        float cn = sigf(G[1])*cp + sigf(G[0])*tanhfast(G[2]);
        float hn = sigf(G[3])*tanhfast(cn);
        c1s[ci*32+bb] = cn;
        AT_STORE(&h1_wr[bb*512 + cell], hn);
        a.h1_all[((size_t)(bb*T_ + t))*512 + cell] = f2bf(hn);
      }
      __syncthreads();
    }
    gbar(a.slots, a.go, genb+4);
  }
}

// ---------- host ----------

extern "C" void kernel_launch(void* const* d_in, const int* in_sizes, int n_in,
                              void* d_out, int out_size, void* d_ws, size_t ws_size,
                              hipStream_t stream){
  const float* enc   = (const float*)d_in[0];
  const int*   caps  = (const int*)d_in[1];
  const float* embW  = (const float*)d_in[2];
  const float* fc_b  = (const float*)d_in[3];
  const float* Wenc  = (const float*)d_in[4];
  const float* benc  = (const float*)d_in[5];
  const float* Wdec  = (const float*)d_in[6];
  const float* bdec  = (const float*)d_in[7];
  const float* Wfull = (const float*)d_in[8];
  const float* bfull = (const float*)d_in[9];
  const float* Wih0  = (const float*)d_in[10];
  const float* Whh0  = (const float*)d_in[11];
  const float* bih0  = (const float*)d_in[12];
  const float* bhh0  = (const float*)d_in[13];
  const float* Wih1  = (const float*)d_in[14];
  const float* Whh1  = (const float*)d_in[15];
  const float* bih1  = (const float*)d_in[16];
  const float* bhh1  = (const float*)d_in[17];
  const float* Winh  = (const float*)d_in[18];
  const float* binh  = (const float*)d_in[19];
  const float* Winc  = (const float*)d_in[20];
  const float* binc  = (const float*)d_in[21];
  float* out = (float*)d_out;

  char* wsp = (char*)d_ws;
  size_t off = 0;
  auto alloc = [&](size_t bytes)->char*{
    char* p = wsp + off;
    off += (bytes + 255) & ~(size_t)255;
    return p;
  };
  u16*   A_enc    = (u16*)  alloc((size_t)6272*512*2);
  u16*   emb_bf   = (u16*)  alloc((size_t)V_*512*2);
  u16*   WencT    = (u16*)  alloc((size_t)512*512*2);
  float* encatt   = (float*)alloc((size_t)6272*512*4);
  u16*   encattBF = (u16*)  alloc((size_t)6272*512*2);
  float* meanb    = (float*)alloc((size_t)32*512*4);
  float* W0f      = (float*)alloc((size_t)2048*1536*4);
  float* W1f      = (float*)alloc((size_t)2048*1024*4);
  float* h0g      = (float*)alloc((size_t)65*SLABF*4);
  float* h1g      = (float*)alloc((size_t)65*SLABF*4);
  float* att2g    = (float*)alloc((size_t)65*SLABF*4);
  float* ctxg     = (float*)alloc((size_t)65*SLABF*4);
  float* c0init   = (float*)alloc(32*512*4);
  float* c1init   = (float*)alloc(32*512*4);
  u16*   h1_all   = (u16*)  alloc((size_t)2048*512*2);
  int*   syncA    = (int*)  alloc(257*4);
  if (off > ws_size) return;
  int* slots = syncA; int* go = syncA + 256;

  // setup
  hipMemsetAsync(syncA, 0, 257*4, stream);
  k_cvt_bf16<<<1568, 256, 0, stream>>>(enc, A_enc, 401408);
  k_cvt_bf16<<<8000, 256, 0, stream>>>(embW, emb_bf, 2048000);
  k_wencT   <<<128, 256, 0, stream>>>(Wenc, WencT);
  k_mean    <<<32, 256, 0, stream>>>(enc, meanb);
  k_init_state<<<256, 256, 0, stream>>>(meanb, Winh, binh, Winc, binc,
                                        h0g, h1g, c0init, c1init);   // slot 0 = init
  k_fuse_w<<<4096, 256, 0, stream>>>(Wih0, Whh0, Wih1, Whh1, W0f, W1f);
  k_gemm_bf16<<<dim3(49, 4), 256, 0, stream>>>(A_enc, WencT, benc, encatt, 512);
  k_cvt_bf16<<<1568, 256, 0, stream>>>(encatt, encattBF, 401408);

  // persistent recurrence (cooperative: guarantees 256-block co-residency)
  RA ra;
  ra.enc = enc; ra.caps = caps; ra.embW = embW;
  ra.Wdec = Wdec; ra.bdec = bdec; ra.Wfull = Wfull; ra.bfull = bfull;
  ra.encattBF = encattBF; ra.W0f = W0f; ra.W1f = W1f;
  ra.bih0 = bih0; ra.bhh0 = bhh0; ra.bih1 = bih1; ra.bhh1 = bhh1;
  ra.h0g = h0g; ra.h1g = h1g; ra.att2g = att2g; ra.ctxg = ctxg;
  ra.c0init = c0init; ra.c1init = c1init;
  ra.h1_all = h1_all; ra.slots = slots; ra.go = go;
  void* kp[] = { &ra };
  hipLaunchCooperativeKernel((const void*)k_recur, dim3(256), dim3(512), kp, 0, stream);

  // deferred tied-weight projection: out[2048][32000] = h1_all @ emb_W^T + fc_b
  k_gemm_bf16<<<dim3(16, 250), 256, 0, stream>>>(h1_all, emb_bf, fc_b, out, V_);
}

// Round 6
// 7847.688 us; speedup vs baseline: 2.1588x; 2.1588x over previous
//
#include <hip/hip_runtime.h>

typedef unsigned short u16;
typedef __attribute__((ext_vector_type(4))) float f32x4;
typedef __attribute__((ext_vector_type(2))) float f32x2;
typedef __attribute__((ext_vector_type(8))) short short8;

#define B_ 32
#define P_ 196
#define T_ 64
#define V_ 32000
#define SLABF 17408   // 64KB data + 4KB guard pad, in floats

// Cross-block exchange: producers use relaxed agent-scope stores (MALL);
// consumers use sc0 loads on t-indexed slabs (proven correct rounds 4-5).
// Flag ordering from __syncthreads() (vmcnt(0) drain before s_barrier).
#define AT_LOAD(p)     __hip_atomic_load((p), __ATOMIC_RELAXED, __HIP_MEMORY_SCOPE_AGENT)
#define AT_STORE(p,v)  __hip_atomic_store((p), (v), __ATOMIC_RELAXED, __HIP_MEMORY_SCOPE_AGENT)

__device__ __forceinline__ u16 f2bf(float x){
  unsigned int u = __float_as_uint(x);
  u += 0x7FFFu + ((u >> 16) & 1u);
  return (u16)(u >> 16);
}
__device__ __forceinline__ float bf2f(u16 x){
  return __uint_as_float(((unsigned int)x) << 16);
}
__device__ __forceinline__ float sigf(float x){ return 1.0f/(1.0f + __expf(-x)); }
__device__ __forceinline__ float tanhfast(float x){
  float e = __expf(-2.0f*fabsf(x));
  float t = (1.0f - e)/(1.0f + e);
  return x >= 0.0f ? t : -t;
}

__device__ __forceinline__ float ld_sc0(const float* p){
  float r;
  asm volatile("global_load_dword %0, %1, off sc0\n\ts_waitcnt vmcnt(0)"
               : "=&v"(r) : "v"(p) : "memory");
  return r;
}

// 4 x dwordx4 sc0 loads (64B contiguous) — only 16 transient VGPRs
__device__ __forceinline__ void ld4_sc0(const float* p, f32x4& a, f32x4& b, f32x4& c, f32x4& d){
  asm volatile(
    "global_load_dwordx4 %0, %4, off sc0\n\t"
    "global_load_dwordx4 %1, %4, off offset:16 sc0\n\t"
    "global_load_dwordx4 %2, %4, off offset:32 sc0\n\t"
    "global_load_dwordx4 %3, %4, off offset:48 sc0\n\t"
    "s_waitcnt vmcnt(0)"
    : "=&v"(a),"=&v"(b),"=&v"(c),"=&v"(d) : "v"(p) : "memory");
}

// ---------- setup kernels ----------

__global__ __launch_bounds__(256) void k_cvt_bf16(const float* __restrict__ s,
                                                  u16* __restrict__ d, int n8){
  int i = blockIdx.x*256 + threadIdx.x;
  if (i >= n8) return;
  const f32x4* sp = (const f32x4*)(s + (size_t)i*8);
  f32x4 a = sp[0], b = sp[1];
  short8 v;
#pragma unroll
  for (int j=0;j<4;++j){ v[j] = (short)f2bf(a[j]); v[4+j] = (short)f2bf(b[j]); }
  *(short8*)(d + (size_t)i*8) = v;
}

__global__ __launch_bounds__(256) void k_wencT(const float* __restrict__ W, u16* __restrict__ WT){
  int tid = threadIdx.x;
  int kc = tid & 63, a = blockIdx.x*4 + (tid >> 6);
  short8 v;
#pragma unroll
  for (int j=0;j<8;++j) v[j] = (short)f2bf(W[(kc*8+j)*512 + a]);
  *(short8*)(WT + a*512 + kc*8) = v;
}

__global__ __launch_bounds__(256) void k_mean(const float* __restrict__ enc, float* __restrict__ mean){
  int b = blockIdx.x, tid = threadIdx.x;
  f32x2 acc; acc.x = 0.f; acc.y = 0.f;
  for (int p=0;p<P_;++p){
    f32x2 v = *(const f32x2*)(enc + ((size_t)(b*P_+p))*512 + tid*2);
    acc.x += v.x; acc.y += v.y;
  }
  acc.x *= (1.0f/196.0f); acc.y *= (1.0f/196.0f);
  *(f32x2*)(mean + b*512 + tid*2) = acc;
}

__global__ __launch_bounds__(256) void k_init_state(const float* __restrict__ mean,
    const float* __restrict__ Wh, const float* __restrict__ bh,
    const float* __restrict__ Wc, const float* __restrict__ bc,
    float* __restrict__ h0, float* __restrict__ h1,
    float* __restrict__ c0, float* __restrict__ c1){
  int bid = blockIdx.x;
  int which = bid >> 7, r = (bid >> 2) & 31, jg = bid & 3;
  const float* W = which ? Wc : Wh;
  const float* bb = which ? bc : bh;
  __shared__ float m[512];
  for (int i=threadIdx.x; i<512; i+=256) m[i] = mean[r*512 + i];
  __syncthreads();
  int j = jg*256 + threadIdx.x;
  float acc = bb[j];
  for (int e=0;e<512;++e) acc += m[e]*W[e*1024 + j];
  int l = r >> 4;
  int bb2 = ((r & 15) << 1) | (j >> 9);
  int hh = j & 511;
  float* dst = which ? (l ? c1 : c0) : (l ? h1 : h0);
  dst[bb2*512 + hh] = acc;
}

// fused LSTM weights: W0f[2048][1536] = [Wih0 | Whh0], W1f[2048][1024] = [Wih1 | Whh1]
__global__ __launch_bounds__(256) void k_fuse_w(const float* __restrict__ Wih0,
    const float* __restrict__ Whh0, const float* __restrict__ Wih1,
    const float* __restrict__ Whh1, float* __restrict__ W0f, float* __restrict__ W1f){
  int r = blockIdx.x, tid = threadIdx.x;
  if (r < 2048){
    for (int k=tid; k<1536; k+=256)
      W0f[(size_t)r*1536+k] = (k<1024) ? Wih0[(size_t)r*1024+k] : Whh0[(size_t)r*512 + (k-1024)];
  } else {
    int r1 = r - 2048;
    for (int k=tid; k<1024; k+=256)
      W1f[(size_t)r1*1024+k] = (k<512) ? Wih1[(size_t)r1*512+k] : Whh1[(size_t)r1*512 + (k-512)];
  }
}

// ---------- bf16 GEMM (LDS pad 40 u16): C[M][N] = A[M][512]*Bm[N][512]^T + bias ----------
#define LDAP 40
__global__ __launch_bounds__(256) void k_gemm_bf16(
    const u16* __restrict__ A, const u16* __restrict__ Bm,
    const float* __restrict__ bias, float* __restrict__ C, int N){
  __shared__ __align__(16) u16 As[128*LDAP];
  __shared__ __align__(16) u16 Bs[128*LDAP];
  int tid = threadIdx.x, l = tid & 63, w = tid >> 6;
  int m0 = blockIdx.x * 128, n0 = blockIdx.y * 128;
  int wm = w >> 1, wn = w & 1;
  f32x4 acc[4][4];
#pragma unroll
  for (int a=0;a<4;++a)
#pragma unroll
    for (int b=0;b<4;++b) acc[a][b] = (f32x4)0.0f;
  int srow = tid >> 2, schunk = tid & 3;
  const u16* gA = A + (size_t)(m0 + srow)*512 + schunk*8;
  const u16* gB = Bm + (size_t)(n0 + srow)*512 + schunk*8;
  int lr = l & 15, lk = (l >> 4) * 8;
  for (int k0 = 0; k0 < 512; k0 += 32){
    short8 va0 = *(const short8*)(gA + k0);
    short8 va1 = *(const short8*)(gA + (size_t)64*512 + k0);
    short8 vb0 = *(const short8*)(gB + k0);
    short8 vb1 = *(const short8*)(gB + (size_t)64*512 + k0);
    __syncthreads();
    *(short8*)(As + srow*LDAP + schunk*8) = va0;
    *(short8*)(As + (64+srow)*LDAP + schunk*8) = va1;
    *(short8*)(Bs + srow*LDAP + schunk*8) = vb0;
    *(short8*)(Bs + (64+srow)*LDAP + schunk*8) = vb1;
    __syncthreads();
    short8 af[4], bfv[4];
#pragma unroll
    for (int mt=0; mt<4; ++mt) af[mt]  = *(const short8*)(As + (wm*64 + mt*16 + lr)*LDAP + lk);
#pragma unroll
    for (int nt=0; nt<4; ++nt) bfv[nt] = *(const short8*)(Bs + (wn*64 + nt*16 + lr)*LDAP + lk);
#pragma unroll
    for (int mt=0; mt<4; ++mt)
#pragma unroll
      for (int nt=0; nt<4; ++nt)
        acc[mt][nt] = __builtin_amdgcn_mfma_f32_16x16x32_bf16(af[mt], bfv[nt], acc[mt][nt], 0, 0, 0);
  }
#pragma unroll
  for (int mt=0; mt<4; ++mt){
    int row = m0 + wm*64 + mt*16 + ((l >> 4) << 2);
#pragma unroll
    for (int nt=0; nt<4; ++nt){
      int col = n0 + wn*64 + nt*16 + (l & 15);
      float bv = bias[col];
#pragma unroll
      for (int j=0;j<4;++j)
        C[(size_t)(row + j)*N + col] = acc[mt][nt][j] + bv;
    }
  }
}

// ---------- persistent recurrence kernel ----------

struct RA {
  const float* enc; const int* caps; const float* embW;
  const u16* WdecBF; const float* bdec; const float* Wfull; const float* bfull;
  const u16* encattBF; const float* W0f; const float* W1f;
  const float* bih0; const float* bhh0; const float* bih1; const float* bhh1;
  float* h0g; float* h1g; float* att2g; float* ctxg;    // t-indexed slabs
  const float* c0init; const float* c1init;
  u16* h1_all; int* slots; int* go;
};

__device__ __forceinline__ void gbar(int* slots, int* go, int gen){
  __syncthreads();
  if (blockIdx.x == 0){
    int tid = threadIdx.x;
    if (tid >= 1 && tid < 256){
      while (AT_LOAD(&slots[tid]) < gen) __builtin_amdgcn_s_sleep(1);
    }
    __syncthreads();
    if (tid == 0) AT_STORE(go, gen);
  } else {
    if (threadIdx.x == 0){
      AT_STORE(&slots[blockIdx.x], gen);
      while (AT_LOAD(go) < gen) __builtin_amdgcn_s_sleep(1);
    }
    __syncthreads();
  }
}

// x chunk layout: xs[b][pi(k)] with pi(16a+4q+c) = 64q+4a+c, batch stride 264.
// -> every ds_read/write_b128's consecutive-8-lane group hits 8 distinct bank quads.

__global__ __launch_bounds__(512, 1) void k_recur(RA a){
  int bid = blockIdx.x, tid = threadIdx.x;
  int lane = tid & 63, wv = tid >> 6;
  __shared__ __align__(16) float w0s[12672];  // 8 rows x (6 ch x 264)
  __shared__ __align__(16) float w1s[8448];   // 8 rows x (4 ch x 264)
  __shared__ __align__(16) float xs[8448];    // 32 b x 264 (one 256-chunk)
  __shared__ float red[1280];
  __shared__ float gsum[256];
  __shared__ float c0s[64], c1s[64];
  __shared__ float SinvS;
  __shared__ int capl[32];

  int ab = (bid & 7)*4 + (bid >> 6);   // batch 0..31 (XCD-grouped)
  int as = (bid >> 3) & 7;             // col-slice 0..7
  int c0col = as*64;
  int sb = tid >> 4, seg = tid & 15;                     // staging map
  int ksg = tid & 15, bq = (tid >> 4) & 7, rp = tid >> 7; // compute map (rows 2rp,2rp+1; batches bq+8*b4)

  // ---- one-time: weights into LDS (swizzled), row r = g*2+ci -> global g*512+bid*2+ci
  for (int idx = tid; idx < 12672; idx += 512){
    int r = idx / 1584, rem = idx - r*1584;
    int ch = rem / 264, pos = rem - ch*264;
    if (ch < 6 && pos < 256){
      int q = pos >> 6, aa = (pos >> 2) & 15, c = pos & 3;
      int k = ch*256 + aa*16 + q*4 + c;
      int grow = (r >> 1)*512 + bid*2 + (r & 1);
      w0s[idx] = a.W0f[(size_t)grow*1536 + k];
    }
  }
  for (int idx = tid; idx < 8448; idx += 512){
    int r = idx / 1056, rem = idx - r*1056;
    int ch = rem / 264, pos = rem - ch*264;
    if (pos < 256){
      int q = pos >> 6, aa = (pos >> 2) & 15, c = pos & 3;
      int k = ch*256 + aa*16 + q*4 + c;
      int grow = (r >> 1)*512 + bid*2 + (r & 1);
      w1s[idx] = a.W1f[(size_t)grow*1024 + k];
    }
  }
  if (tid < 64){
    int ci = tid >> 5, b = tid & 31, cell = bid*2 + ci;
    c0s[ci*32+b] = a.c0init[b*512 + cell];
    c1s[ci*32+b] = a.c1init[b*512 + cell];
  }
  __syncthreads();

  for (int t = 0; t < T_; ++t){
    const float* h1_rd  = a.h1g  + (size_t)t*SLABF;        // h1(t-1); slot0 = init
    const float* h0_rd  = a.h0g  + (size_t)t*SLABF;
    float*       h0_wr  = a.h0g  + (size_t)(t+1)*SLABF;
    float*       h1_wr  = a.h1g  + (size_t)(t+1)*SLABF;
    float*       at_wr  = a.att2g + (size_t)t*SLABF;
    const float* at_rd  = at_wr;
    float*       cx_wr  = a.ctxg + (size_t)t*SLABF;
    const float* cx_rd  = cx_wr;
    int genb = t*4;

    // ---- P1: att2 cols [c0col, c0col+64) for batch ab ----
    {
      float* h1s = red; float* gp = red + 512;
      h1s[tid] = ld_sc0(&h1_rd[ab*512 + tid]);
      __syncthreads();
      int c = lane, ksx = wv;
      float accp = 0.f;
      const u16* wpd = a.WdecBF + (size_t)(ksx*64)*512 + c0col + c;
#pragma unroll 8
      for (int i=0;i<64;++i) accp = fmaf(h1s[ksx*64+i], bf2f(wpd[(size_t)i*512]), accp);
      gp[ksx*64+c] = accp;
      __syncthreads();
      if (tid < 64){
        float s = a.bdec[c0col+tid];
#pragma unroll
        for (int k=0;k<8;++k) s += gp[k*64+tid];
        AT_STORE(&at_wr[ab*512 + c0col + tid], s);
      }
    }
    gbar(a.slots, a.go, genb+1);

    // ---- P23: logits+softmax (redundant per batch group) + ctx cols ----
    {
      float* att2s = red; float* gp3 = red + 512; float* alph = red + 1024;
      att2s[tid] = ld_sc0(&at_rd[ab*512 + tid]);
      __syncthreads();
      float a2[8], wf[8];
#pragma unroll
      for (int j=0;j<8;++j){ a2[j] = att2s[lane*8+j]; wf[j] = a.Wfull[lane*8+j]; }
      float bf0 = a.bfull[0];
      int np = (wv < 4) ? 25 : 24;
      for (int i=0;i<np;++i){
        int p = wv + i*8;
        const u16* ep = a.encattBF + ((size_t)(ab*P_ + p))*512 + lane*8;
        short8 ev = *(const short8*)ep;
        float s = 0.f;
#pragma unroll
        for (int j=0;j<8;++j)
          s += fmaxf(bf2f((u16)ev[j]) + a2[j], 0.f) * wf[j];
#pragma unroll
        for (int o=32;o>=1;o>>=1) s += __shfl_xor(s, o);
        if (lane == 0) alph[p] = __expf(s + bf0);
      }
      __syncthreads();
      if (wv == 0){
        float v = 0.f;
#pragma unroll
        for (int i=0;i<4;++i){ int p = lane + 64*i; if (p < P_) v += alph[p]; }
#pragma unroll
        for (int o=32;o>=1;o>>=1) v += __shfl_xor(v, o);
        if (lane == 0) SinvS = 1.0f / v;
      }
      int c = lane, pk = wv;
      float accp = 0.f;
      for (int i=0;i<25;++i){
        int p = pk + 8*i;
        if (p < P_) accp = fmaf(alph[p], a.enc[((size_t)(ab*P_ + p))*512 + c0col + c], accp);
      }
      gp3[pk*64+c] = accp;
      __syncthreads();
      if (tid < 64){
        float s = 0.f;
#pragma unroll
        for (int k=0;k<8;++k) s += gp3[k*64+tid];
        AT_STORE(&cx_wr[ab*512 + c0col + tid], s * SinvS);
      }
    }
    gbar(a.slots, a.go, genb+2);

    // ---- P4: LSTM layer 0 (block owns cells bid*2, bid*2+1) ----
    {
      if (tid < 32) capl[tid] = a.caps[tid*T_ + t];
      float acc0[4], acc1[4];
#pragma unroll
      for (int i=0;i<4;++i){ acc0[i]=0.f; acc1[i]=0.f; }
      const float* w0base = w0s + (rp*2)*1584 + ksg*4;
      for (int ch=0; ch<6; ++ch){
        __syncthreads();
        {
          f32x4 va, vb, vc, vd;
          if (ch < 2){
            const float* src = a.embW + (size_t)capl[sb]*512 + ch*256 + seg*16;
            va = *(const f32x4*)(src);
            vb = *(const f32x4*)(src+4);
            vc = *(const f32x4*)(src+8);
            vd = *(const f32x4*)(src+12);
          } else {
            const float* src = (ch < 4) ? (cx_rd + sb*512 + (ch-2)*256 + seg*16)
                                        : (h0_rd + sb*512 + (ch-4)*256 + seg*16);
            ld4_sc0(src, va, vb, vc, vd);
          }
          float* xb = xs + sb*264 + seg*4;
          *(f32x4*)(xb      ) = va;
          *(f32x4*)(xb + 64 ) = vb;
          *(f32x4*)(xb + 128) = vc;
          *(f32x4*)(xb + 192) = vd;
        }
        __syncthreads();
        const float* w0 = w0base + ch*264;
#pragma unroll
        for (int q=0;q<4;++q){
          f32x4 wa = *(const f32x4*)(w0 + q*64);
          f32x4 wb = *(const f32x4*)(w0 + 1584 + q*64);
#pragma unroll
          for (int b4=0;b4<4;++b4){
            f32x4 x4 = *(const f32x4*)(xs + (bq + 8*b4)*264 + q*64 + ksg*4);
            acc0[b4] = fmaf(wa.x,x4.x, fmaf(wa.y,x4.y, fmaf(wa.z,x4.z, fmaf(wa.w,x4.w, acc0[b4]))));
            acc1[b4] = fmaf(wb.x,x4.x, fmaf(wb.y,x4.y, fmaf(wb.z,x4.z, fmaf(wb.w,x4.w, acc1[b4]))));
          }
        }
      }
#pragma unroll
      for (int b4=0;b4<4;++b4){
        float v0 = acc0[b4], v1 = acc1[b4];
        v0 += __shfl_xor(v0,1); v0 += __shfl_xor(v0,2); v0 += __shfl_xor(v0,4); v0 += __shfl_xor(v0,8);
        v1 += __shfl_xor(v1,1); v1 += __shfl_xor(v1,2); v1 += __shfl_xor(v1,4); v1 += __shfl_xor(v1,8);
        if (ksg == 0){
          gsum[(rp*2    )*32 + bq + 8*b4] = v0;   // row = g*2+ci
          gsum[(rp*2 + 1)*32 + bq + 8*b4] = v1;
        }
      }
      __syncthreads();
      if (tid < 64){
        int ci = tid >> 5, bb = tid & 31, cell = bid*2 + ci;
        float G[4];
#pragma unroll
        for (int g=0;g<4;++g)
          G[g] = gsum[(g*2+ci)*32 + bb] + a.bih0[g*512+cell] + a.bhh0[g*512+cell];
        float cp = c0s[ci*32+bb];
        float cn = sigf(G[1])*cp + sigf(G[0])*tanhfast(G[2]);
        float hn = sigf(G[3])*tanhfast(cn);
        c0s[ci*32+bb] = cn;
        AT_STORE(&h0_wr[bb*512 + cell], hn);
      }
    }
    gbar(a.slots, a.go, genb+3);

    // ---- P5: LSTM layer 1 ----
    {
      float acc0[4], acc1[4];
#pragma unroll
      for (int i=0;i<4;++i){ acc0[i]=0.f; acc1[i]=0.f; }
      const float* w1base = w1s + (rp*2)*1056 + ksg*4;
      for (int ch=0; ch<4; ++ch){
        __syncthreads();
        {
          f32x4 va, vb, vc, vd;
          const float* src = (ch < 2) ? (h0_wr + sb*512 + ch*256 + seg*16)
                                      : (h1_rd + sb*512 + (ch-2)*256 + seg*16);
          ld4_sc0(src, va, vb, vc, vd);
          float* xb = xs + sb*264 + seg*4;
          *(f32x4*)(xb      ) = va;
          *(f32x4*)(xb + 64 ) = vb;
          *(f32x4*)(xb + 128) = vc;
          *(f32x4*)(xb + 192) = vd;
        }
        __syncthreads();
        const float* w1 = w1base + ch*264;
#pragma unroll
        for (int q=0;q<4;++q){
          f32x4 wa = *(const f32x4*)(w1 + q*64);
          f32x4 wb = *(const f32x4*)(w1 + 1056 + q*64);
#pragma unroll
          for (int b4=0;b4<4;++b4){
            f32x4 x4 = *(const f32x4*)(xs + (bq + 8*b4)*264 + q*64 + ksg*4);
            acc0[b4] = fmaf(wa.x,x4.x, fmaf(wa.y,x4.y, fmaf(wa.z,x4.z, fmaf(wa.w,x4.w, acc0[b4]))));
            acc1[b4] = fmaf(wb.x,x4.x, fmaf(wb.y,x4.y, fmaf(wb.z,x4.z, fmaf(wb.w,x4.w, acc1[b4]))));
          }
        }
      }
#pragma unroll
      for (int b4=0;b4<4;++b4){
        float v0 = acc0[b4], v1 = acc1[b4];
        v0 += __shfl_xor(v0,1); v0 += __shfl_xor(v0,2); v0 += __shfl_xor(v0,4); v0 += __shfl_xor(v0,8);
        v1 += __shfl_xor(v1,1); v1 += __shfl_xor(v1,2); v1 += __shfl_xor(v1,4); v1 += __shfl_xor(v1,8);
        if (ksg == 0){
          gsum[(rp*2    )*32 + bq + 8*b4] = v0;
          gsum[(rp*2 + 1)*32 + bq + 8*b4] = v1;
        }
      }
      __syncthreads();
      if (tid < 64){
        int ci = tid >> 5, bb = tid & 31, cell = bid*2 + ci;
        float G[4];
#pragma unroll
        for (int g=0;g<4;++g)
          G[g] = gsum[(g*2+ci)*32 + bb] + a.bih1[g*512+cell] + a.bhh1[g*512+cell];
        float cp = c1s[ci*32+bb];
        float cn = sigf(G[1])*cp + sigf(G[0])*tanhfast(G[2]);
        float hn = sigf(G[3])*tanhfast(cn);
        c1s[ci*32+bb] = cn;
        AT_STORE(&h1_wr[bb*512 + cell], hn);
        a.h1_all[((size_t)(bb*T_ + t))*512 + cell] = f2bf(hn);
      }
    }
    gbar(a.slots, a.go, genb+4);
  }
}

// ---------- host ----------

extern "C" void kernel_launch(void* const* d_in, const int* in_sizes, int n_in,
                              void* d_out, int out_size, void* d_ws, size_t ws_size,
                              hipStream_t stream){
  const float* enc   = (const float*)d_in[0];
  const int*   caps  = (const int*)d_in[1];
  const float* embW  = (const float*)d_in[2];
  const float* fc_b  = (const float*)d_in[3];
  const float* Wenc  = (const float*)d_in[4];
  const float* benc  = (const float*)d_in[5];
  const float* Wdec  = (const float*)d_in[6];
  const float* bdec  = (const float*)d_in[7];
  const float* Wfull = (const float*)d_in[8];
  const float* bfull = (const float*)d_in[9];
  const float* Wih0  = (const float*)d_in[10];
  const float* Whh0  = (const float*)d_in[11];
  const float* bih0  = (const float*)d_in[12];
  const float* bhh0  = (const float*)d_in[13];
  const float* Wih1  = (const float*)d_in[14];
  const float* Whh1  = (const float*)d_in[15];
  const float* bih1  = (const float*)d_in[16];
  const float* bhh1  = (const float*)d_in[17];
  const float* Winh  = (const float*)d_in[18];
  const float* binh  = (const float*)d_in[19];
  const float* Winc  = (const float*)d_in[20];
  const float* binc  = (const float*)d_in[21];
  float* out = (float*)d_out;

  char* wsp = (char*)d_ws;
  size_t off = 0;
  auto alloc = [&](size_t bytes)->char*{
    char* p = wsp + off;
    off += (bytes + 255) & ~(size_t)255;
    return p;
  };
  u16*   A_enc    = (u16*)  alloc((size_t)6272*512*2);
  u16*   emb_bf   = (u16*)  alloc((size_t)V_*512*2);
  u16*   WencT    = (u16*)  alloc((size_t)512*512*2);
  u16*   WdecBF   = (u16*)  alloc((size_t)512*512*2);
  float* encatt   = (float*)alloc((size_t)6272*512*4);
  u16*   encattBF = (u16*)  alloc((size_t)6272*512*2);
  float* meanb    = (float*)alloc((size_t)32*512*4);
  float* W0f      = (float*)alloc((size_t)2048*1536*4);
  float* W1f      = (float*)alloc((size_t)2048*1024*4);
  float* h0g      = (float*)alloc((size_t)65*SLABF*4);
  float* h1g      = (float*)alloc((size_t)65*SLABF*4);
  float* att2g    = (float*)alloc((size_t)65*SLABF*4);
  float* ctxg     = (float*)alloc((size_t)65*SLABF*4);
  float* c0init   = (float*)alloc(32*512*4);
  float* c1init   = (float*)alloc(32*512*4);
  u16*   h1_all   = (u16*)  alloc((size_t)2048*512*2);
  int*   syncA    = (int*)  alloc(257*4);
  if (off > ws_size) return;
  int* slots = syncA; int* go = syncA + 256;

  // setup
  hipMemsetAsync(syncA, 0, 257*4, stream);
  k_cvt_bf16<<<1568, 256, 0, stream>>>(enc, A_enc, 401408);
  k_cvt_bf16<<<8000, 256, 0, stream>>>(embW, emb_bf, 2048000);
  k_cvt_bf16<<<128, 256, 0, stream>>>(Wdec, WdecBF, 32768);
  k_wencT   <<<128, 256, 0, stream>>>(Wenc, WencT);
  k_mean    <<<32, 256, 0, stream>>>(enc, meanb);
  k_init_state<<<256, 256, 0, stream>>>(meanb, Winh, binh, Winc, binc,
                                        h0g, h1g, c0init, c1init);   // slot 0 = init
  k_fuse_w<<<4096, 256, 0, stream>>>(Wih0, Whh0, Wih1, Whh1, W0f, W1f);
  k_gemm_bf16<<<dim3(49, 4), 256, 0, stream>>>(A_enc, WencT, benc, encatt, 512);
  k_cvt_bf16<<<1568, 256, 0, stream>>>(encatt, encattBF, 401408);

  // persistent recurrence (cooperative: guarantees 256-block co-residency)
  RA ra;
  ra.enc = enc; ra.caps = caps; ra.embW = embW;
  ra.WdecBF = WdecBF; ra.bdec = bdec; ra.Wfull = Wfull; ra.bfull = bfull;
  ra.encattBF = encattBF; ra.W0f = W0f; ra.W1f = W1f;
  ra.bih0 = bih0; ra.bhh0 = bhh0; ra.bih1 = bih1; ra.bhh1 = bhh1;
  ra.h0g = h0g; ra.h1g = h1g; ra.att2g = att2g; ra.ctxg = ctxg;
  ra.c0init = c0init; ra.c1init = c1init;
  ra.h1_all = h1_all; ra.slots = slots; ra.go = go;
  void* kp[] = { &ra };
  hipLaunchCooperativeKernel((const void*)k_recur, dim3(256), dim3(512), kp, 0, stream);

  // deferred tied-weight projection: out[2048][32000] = h1_all @ emb_W^T + fc_b
  k_gemm_bf16<<<dim3(16, 250), 256, 0, stream>>>(h1_all, emb_bf, fc_b, out, V_);
}

// Round 7
// 5333.872 us; speedup vs baseline: 3.1762x; 1.4713x over previous
//
#include <hip/hip_runtime.h>

typedef unsigned short u16;
typedef __attribute__((ext_vector_type(4))) float f32x4;
typedef __attribute__((ext_vector_type(2))) float f32x2;
typedef __attribute__((ext_vector_type(8))) short short8;

#define B_ 32
#define P_ 196
#define T_ 64
#define V_ 32000
#define SLABF 17408   // 68 KB slab stride in floats (64KB data + guard)

// Cross-block exchange protocol (proven rounds 4-6):
//   producers: relaxed device-scope atomic stores (write-through to MALL).
//   consumers: PLAIN cached loads on t-indexed slabs. Safe because each slab
//   address is never read before its producer writes it (fresh per step), so
//   no stale L1/L2 line can exist; plain miss -> MALL -> fills L2 so the 32
//   blocks of an XCD dedup the broadcast. Across graph replays cached lines
//   hold bit-identical values (deterministic kernel). Flag ordering comes
//   from __syncthreads() (vmcnt drain) before the flag store; a compiler
//   fence after the poll stops load hoisting.
#define AT_LOAD(p)     __hip_atomic_load((p), __ATOMIC_RELAXED, __HIP_MEMORY_SCOPE_AGENT)
#define AT_STORE(p,v)  __hip_atomic_store((p), (v), __ATOMIC_RELAXED, __HIP_MEMORY_SCOPE_AGENT)

__device__ __forceinline__ u16 f2bf(float x){
  unsigned int u = __float_as_uint(x);
  u += 0x7FFFu + ((u >> 16) & 1u);
  return (u16)(u >> 16);
}
__device__ __forceinline__ float bf2f(u16 x){
  return __uint_as_float(((unsigned int)x) << 16);
}
__device__ __forceinline__ float sigf(float x){ return 1.0f/(1.0f + __expf(-x)); }
__device__ __forceinline__ float tanhfast(float x){
  float e = __expf(-2.0f*fabsf(x));
  float t = (1.0f - e)/(1.0f + e);
  return x >= 0.0f ? t : -t;
}

// ---------- setup kernels ----------

__global__ __launch_bounds__(256) void k_cvt_bf16(const float* __restrict__ s,
                                                  u16* __restrict__ d, int n8){
  int i = blockIdx.x*256 + threadIdx.x;
  if (i >= n8) return;
  const f32x4* sp = (const f32x4*)(s + (size_t)i*8);
  f32x4 a = sp[0], b = sp[1];
  short8 v;
#pragma unroll
  for (int j=0;j<4;++j){ v[j] = (short)f2bf(a[j]); v[4+j] = (short)f2bf(b[j]); }
  *(short8*)(d + (size_t)i*8) = v;
}

__global__ __launch_bounds__(256) void k_wencT(const float* __restrict__ W, u16* __restrict__ WT){
  int tid = threadIdx.x;
  int kc = tid & 63, a = blockIdx.x*4 + (tid >> 6);
  short8 v;
#pragma unroll
  for (int j=0;j<8;++j) v[j] = (short)f2bf(W[(kc*8+j)*512 + a]);
  *(short8*)(WT + a*512 + kc*8) = v;
}

__global__ __launch_bounds__(256) void k_mean(const float* __restrict__ enc, float* __restrict__ mean){
  int b = blockIdx.x, tid = threadIdx.x;
  f32x2 acc; acc.x = 0.f; acc.y = 0.f;
  for (int p=0;p<P_;++p){
    f32x2 v = *(const f32x2*)(enc + ((size_t)(b*P_+p))*512 + tid*2);
    acc.x += v.x; acc.y += v.y;
  }
  acc.x *= (1.0f/196.0f); acc.y *= (1.0f/196.0f);
  *(f32x2*)(mean + b*512 + tid*2) = acc;
}

__global__ __launch_bounds__(256) void k_init_state(const float* __restrict__ mean,
    const float* __restrict__ Wh, const float* __restrict__ bh,
    const float* __restrict__ Wc, const float* __restrict__ bc,
    float* __restrict__ h0, float* __restrict__ h1,
    float* __restrict__ c0, float* __restrict__ c1){
  int bid = blockIdx.x;
  int which = bid >> 7, r = (bid >> 2) & 31, jg = bid & 3;
  const float* W = which ? Wc : Wh;
  const float* bb = which ? bc : bh;
  __shared__ float m[512];
  for (int i=threadIdx.x; i<512; i+=256) m[i] = mean[r*512 + i];
  __syncthreads();
  int j = jg*256 + threadIdx.x;
  float acc = bb[j];
  for (int e=0;e<512;++e) acc += m[e]*W[e*1024 + j];
  int l = r >> 4;
  int bb2 = ((r & 15) << 1) | (j >> 9);
  int hh = j & 511;
  float* dst = which ? (l ? c1 : c0) : (l ? h1 : h0);
  dst[bb2*512 + hh] = acc;
}

// fused LSTM weights: W0f[2048][1536] = [Wih0 | Whh0], W1f[2048][1024] = [Wih1 | Whh1]
__global__ __launch_bounds__(256) void k_fuse_w(const float* __restrict__ Wih0,
    const float* __restrict__ Whh0, const float* __restrict__ Wih1,
    const float* __restrict__ Whh1, float* __restrict__ W0f, float* __restrict__ W1f){
  int r = blockIdx.x, tid = threadIdx.x;
  if (r < 2048){
    for (int k=tid; k<1536; k+=256)
      W0f[(size_t)r*1536+k] = (k<1024) ? Wih0[(size_t)r*1024+k] : Whh0[(size_t)r*512 + (k-1024)];
  } else {
    int r1 = r - 2048;
    for (int k=tid; k<1024; k+=256)
      W1f[(size_t)r1*1024+k] = (k<512) ? Wih1[(size_t)r1*512+k] : Whh1[(size_t)r1*512 + (k-512)];
  }
}

// ---------- bf16 GEMM (LDS pad 40 u16): C[M][N] = A[M][512]*Bm[N][512]^T + bias ----------
#define LDAP 40
__global__ __launch_bounds__(256) void k_gemm_bf16(
    const u16* __restrict__ A, const u16* __restrict__ Bm,
    const float* __restrict__ bias, float* __restrict__ C, int N){
  __shared__ __align__(16) u16 As[128*LDAP];
  __shared__ __align__(16) u16 Bs[128*LDAP];
  int tid = threadIdx.x, l = tid & 63, w = tid >> 6;
  int m0 = blockIdx.x * 128, n0 = blockIdx.y * 128;
  int wm = w >> 1, wn = w & 1;
  f32x4 acc[4][4];
#pragma unroll
  for (int a=0;a<4;++a)
#pragma unroll
    for (int b=0;b<4;++b) acc[a][b] = (f32x4)0.0f;
  int srow = tid >> 2, schunk = tid & 3;
  const u16* gA = A + (size_t)(m0 + srow)*512 + schunk*8;
  const u16* gB = Bm + (size_t)(n0 + srow)*512 + schunk*8;
  int lr = l & 15, lk = (l >> 4) * 8;
  for (int k0 = 0; k0 < 512; k0 += 32){
    short8 va0 = *(const short8*)(gA + k0);
    short8 va1 = *(const short8*)(gA + (size_t)64*512 + k0);
    short8 vb0 = *(const short8*)(gB + k0);
    short8 vb1 = *(const short8*)(gB + (size_t)64*512 + k0);
    __syncthreads();
    *(short8*)(As + srow*LDAP + schunk*8) = va0;
    *(short8*)(As + (64+srow)*LDAP + schunk*8) = va1;
    *(short8*)(Bs + srow*LDAP + schunk*8) = vb0;
    *(short8*)(Bs + (64+srow)*LDAP + schunk*8) = vb1;
    __syncthreads();
    short8 af[4], bfv[4];
#pragma unroll
    for (int mt=0; mt<4; ++mt) af[mt]  = *(const short8*)(As + (wm*64 + mt*16 + lr)*LDAP + lk);
#pragma unroll
    for (int nt=0; nt<4; ++nt) bfv[nt] = *(const short8*)(Bs + (wn*64 + nt*16 + lr)*LDAP + lk);
#pragma unroll
    for (int mt=0; mt<4; ++mt)
#pragma unroll
      for (int nt=0; nt<4; ++nt)
        acc[mt][nt] = __builtin_amdgcn_mfma_f32_16x16x32_bf16(af[mt], bfv[nt], acc[mt][nt], 0, 0, 0);
  }
#pragma unroll
  for (int mt=0; mt<4; ++mt){
    int row = m0 + wm*64 + mt*16 + ((l >> 4) << 2);
#pragma unroll
    for (int nt=0; nt<4; ++nt){
      int col = n0 + wn*64 + nt*16 + (l & 15);
      float bv = bias[col];
#pragma unroll
      for (int j=0;j<4;++j)
        C[(size_t)(row + j)*N + col] = acc[mt][nt][j] + bv;
    }
  }
}

// ---------- persistent recurrence kernel ----------

struct RA {
  const float* enc; const int* caps; const float* embW;
  const u16* WdecBF; const float* bdec; const float* Wfull; const float* bfull;
  const u16* encattBF; const float* W0f; const float* W1f;
  const float* bih0; const float* bhh0; const float* bih1; const float* bhh1;
  float* h0g; float* h1g; float* att2g; float* ctxg;    // t-indexed slabs
  const float* c0init; const float* c1init;
  u16* h1_all; int* slots; int* go;
};

__device__ __forceinline__ void gbar(int* slots, int* go, int gen){
  __syncthreads();
  if (blockIdx.x == 0){
    int tid = threadIdx.x;
    if (tid >= 1 && tid < 256){
      while (AT_LOAD(&slots[tid]) < gen) __builtin_amdgcn_s_sleep(1);
    }
    __syncthreads();
    if (tid == 0) AT_STORE(go, gen);
  } else {
    if (threadIdx.x == 0){
      AT_STORE(&slots[blockIdx.x], gen);
      while (AT_LOAD(go) < gen) __builtin_amdgcn_s_sleep(1);
    }
    __syncthreads();
  }
  asm volatile("" ::: "memory");  // compiler fence: no load hoisting above the poll
}

__global__ __launch_bounds__(512) void k_recur(RA a){
  int bid = blockIdx.x, tid = threadIdx.x;
  int lane = tid & 63, wv = tid >> 6;
  __shared__ float red[2048];          // P1: h1s|gp ; P23: att2s|gp3|alph
  __shared__ float c0s[64], c1s[64];   // [c4*16 + b16]
  __shared__ float SinvS;
  __shared__ int capl[16];

  int xcd = bid & 7;
  // attention role: 4 batches per XCD (encatt L2-resident), 8 col-slices
  int ab = xcd*4 + ((bid >> 3) & 3);
  int as = bid >> 5, c0col = as*64;
  // LSTM role: 16 cell-groups per XCD (weights L2-resident), 2 batch-groups
  int cg = xcd*16 + (bid >> 4);
  int bg = (bid >> 3) & 1;
  int cell0 = cg*4;
  int ksg = tid & 31, b16 = tid >> 5;   // k-slice 0..31 (16 floats), batch 0..15

  if (tid < 64){
    int c4 = tid >> 4, b = tid & 15, bb = bg*16 + b, cell = cell0 + c4;
    c0s[c4*16+b] = a.c0init[bb*512 + cell];
    c1s[c4*16+b] = a.c1init[bb*512 + cell];
  }
  __syncthreads();

  for (int t = 0; t < T_; ++t){
    const float* h1_rd = a.h1g + (size_t)t*SLABF;        // h1(t-1); slot0 = init
    const float* h0_rd = a.h0g + (size_t)t*SLABF;
    float*       h0_wr = a.h0g + (size_t)(t+1)*SLABF;
    float*       h1_wr = a.h1g + (size_t)(t+1)*SLABF;
    float*       at_wr = a.att2g + (size_t)t*SLABF;
    const float* at_rd = at_wr;
    float*       cx_wr = a.ctxg + (size_t)t*SLABF;
    const float* cx_rd = cx_wr;
    int genb = t*4;

    // ---- P1: att2 cols [c0col, c0col+64) for batch ab ----
    {
      float* h1s = red; float* gp = red + 512;
      h1s[tid] = h1_rd[ab*512 + tid];                 // plain cached (fresh slab)
      __syncthreads();
      int c = lane, ksx = wv;
      float accp = 0.f;
      const u16* wpd = a.WdecBF + (size_t)(ksx*64)*512 + c0col + c;
#pragma unroll 8
      for (int i=0;i<64;++i) accp = fmaf(h1s[ksx*64+i], bf2f(wpd[(size_t)i*512]), accp);
      gp[ksx*64+c] = accp;
      __syncthreads();
      if (tid < 64){
        float s = a.bdec[c0col+tid];
#pragma unroll
        for (int k=0;k<8;++k) s += gp[k*64+tid];
        AT_STORE(&at_wr[ab*512 + c0col + tid], s);
      }
    }
    gbar(a.slots, a.go, genb+1);

    // ---- P23: logits + softmax (redundant per block) + ctx col-slice ----
    {
      float* att2s = red; float* gp3 = red + 512; float* alph = red + 1024;
      att2s[tid] = at_rd[ab*512 + tid];               // plain cached
      __syncthreads();
      float a2[8], wf[8];
#pragma unroll
      for (int j=0;j<8;++j){ a2[j] = att2s[lane*8+j]; wf[j] = a.Wfull[lane*8+j]; }
      float bf0 = a.bfull[0];
      int np = (wv < 4) ? 25 : 24;
      for (int i=0;i<np;++i){
        int p = wv + i*8;
        const u16* ep = a.encattBF + ((size_t)(ab*P_ + p))*512 + lane*8;
        short8 ev = *(const short8*)ep;
        float s = 0.f;
#pragma unroll
        for (int j=0;j<8;++j)
          s += fmaxf(bf2f((u16)ev[j]) + a2[j], 0.f) * wf[j];
#pragma unroll
        for (int o=32;o>=1;o>>=1) s += __shfl_xor(s, o);
        if (lane == 0) alph[p] = __expf(s + bf0);
      }
      __syncthreads();
      if (wv == 0){
        float v = 0.f;
#pragma unroll
        for (int i=0;i<4;++i){ int p = lane + 64*i; if (p < P_) v += alph[p]; }
#pragma unroll
        for (int o=32;o>=1;o>>=1) v += __shfl_xor(v, o);
        if (lane == 0) SinvS = 1.0f / v;
      }
      int c = lane, pk = wv;
      float accp = 0.f;
      for (int i=0;i<25;++i){
        int p = pk + 8*i;
        if (p < P_) accp = fmaf(alph[p], a.enc[((size_t)(ab*P_ + p))*512 + c0col + c], accp);
      }
      gp3[pk*64+c] = accp;
      __syncthreads();
      if (tid < 64){
        float s = 0.f;
#pragma unroll
        for (int k=0;k<8;++k) s += gp3[k*64+tid];
        AT_STORE(&cx_wr[ab*512 + c0col + tid], s * SinvS);
      }
    }
    gbar(a.slots, a.go, genb+2);

    // ---- P4: LSTM layer 0 — block owns cells cell0..cell0+3, batches bg*16.. ----
    {
      if (tid < 16) capl[tid] = a.caps[(bg*16+tid)*T_ + t];
      __syncthreads();
      float acc[16];
#pragma unroll
      for (int r=0;r<16;++r) acc[r] = 0.f;
      int bb = bg*16 + b16;
#pragma unroll
      for (int ch=0; ch<3; ++ch){
        const float* src;
        if (ch == 0)      src = a.embW + (size_t)capl[b16]*512 + ksg*16;
        else if (ch == 1) src = cx_rd + bb*512 + ksg*16;       // plain cached slab
        else              src = h0_rd + bb*512 + ksg*16;
        f32x4 x0 = *(const f32x4*)(src);
        f32x4 x1 = *(const f32x4*)(src+4);
        f32x4 x2 = *(const f32x4*)(src+8);
        f32x4 x3 = *(const f32x4*)(src+12);
#pragma unroll
        for (int r=0;r<16;++r){
          int grow = (r>>2)*512 + cell0 + (r&3);
          const float* wp = a.W0f + (size_t)grow*1536 + ch*512 + ksg*16;
          f32x4 w0 = *(const f32x4*)(wp);
          f32x4 w1 = *(const f32x4*)(wp+4);
          f32x4 w2 = *(const f32x4*)(wp+8);
          f32x4 w3 = *(const f32x4*)(wp+12);
          float s = acc[r];
          s = fmaf(x0.x,w0.x, fmaf(x0.y,w0.y, fmaf(x0.z,w0.z, fmaf(x0.w,w0.w, s))));
          s = fmaf(x1.x,w1.x, fmaf(x1.y,w1.y, fmaf(x1.z,w1.z, fmaf(x1.w,w1.w, s))));
          s = fmaf(x2.x,w2.x, fmaf(x2.y,w2.y, fmaf(x2.z,w2.z, fmaf(x2.w,w2.w, s))));
          s = fmaf(x3.x,w3.x, fmaf(x3.y,w3.y, fmaf(x3.z,w3.z, fmaf(x3.w,w3.w, s))));
          acc[r] = s;
        }
      }
#pragma unroll
      for (int r=0;r<16;++r){
        float v = acc[r];
        v += __shfl_xor(v,1); v += __shfl_xor(v,2); v += __shfl_xor(v,4);
        v += __shfl_xor(v,8); v += __shfl_xor(v,16);
        acc[r] = v;
      }
      if (ksg == 0){   // 16 lanes, one per batch: finalize all 4 cells
#pragma unroll
        for (int c4=0;c4<4;++c4){
          int cell = cell0 + c4;
          float gi = acc[0*4+c4] + a.bih0[cell]        + a.bhh0[cell];
          float gf = acc[1*4+c4] + a.bih0[512+cell]    + a.bhh0[512+cell];
          float gg = acc[2*4+c4] + a.bih0[1024+cell]   + a.bhh0[1024+cell];
          float go = acc[3*4+c4] + a.bih0[1536+cell]   + a.bhh0[1536+cell];
          float cp = c0s[c4*16+b16];
          float cn = sigf(gf)*cp + sigf(gi)*tanhfast(gg);
          float hn = sigf(go)*tanhfast(cn);
          c0s[c4*16+b16] = cn;
          AT_STORE(&h0_wr[bb*512 + cell], hn);
        }
      }
    }
    gbar(a.slots, a.go, genb+3);

    // ---- P5: LSTM layer 1 ----
    {
      float acc[16];
#pragma unroll
      for (int r=0;r<16;++r) acc[r] = 0.f;
      int bb = bg*16 + b16;
#pragma unroll
      for (int ch=0; ch<2; ++ch){
        const float* src = (ch == 0) ? (h0_wr + bb*512 + ksg*16)
                                     : (h1_rd + bb*512 + ksg*16);
        f32x4 x0 = *(const f32x4*)(src);
        f32x4 x1 = *(const f32x4*)(src+4);
        f32x4 x2 = *(const f32x4*)(src+8);
        f32x4 x3 = *(const f32x4*)(src+12);
#pragma unroll
        for (int r=0;r<16;++r){
          int grow = (r>>2)*512 + cell0 + (r&3);
          const float* wp = a.W1f + (size_t)grow*1024 + ch*512 + ksg*16;
          f32x4 w0 = *(const f32x4*)(wp);
          f32x4 w1 = *(const f32x4*)(wp+4);
          f32x4 w2 = *(const f32x4*)(wp+8);
          f32x4 w3 = *(const f32x4*)(wp+12);
          float s = acc[r];
          s = fmaf(x0.x,w0.x, fmaf(x0.y,w0.y, fmaf(x0.z,w0.z, fmaf(x0.w,w0.w, s))));
          s = fmaf(x1.x,w1.x, fmaf(x1.y,w1.y, fmaf(x1.z,w1.z, fmaf(x1.w,w1.w, s))));
          s = fmaf(x2.x,w2.x, fmaf(x2.y,w2.y, fmaf(x2.z,w2.z, fmaf(x2.w,w2.w, s))));
          s = fmaf(x3.x,w3.x, fmaf(x3.y,w3.y, fmaf(x3.z,w3.z, fmaf(x3.w,w3.w, s))));
          acc[r] = s;
        }
      }
#pragma unroll
      for (int r=0;r<16;++r){
        float v = acc[r];
        v += __shfl_xor(v,1); v += __shfl_xor(v,2); v += __shfl_xor(v,4);
        v += __shfl_xor(v,8); v += __shfl_xor(v,16);
        acc[r] = v;
      }
      if (ksg == 0){
#pragma unroll
        for (int c4=0;c4<4;++c4){
          int cell = cell0 + c4;
          float gi = acc[0*4+c4] + a.bih1[cell]        + a.bhh1[cell];
          float gf = acc[1*4+c4] + a.bih1[512+cell]    + a.bhh1[512+cell];
          float gg = acc[2*4+c4] + a.bih1[1024+cell]   + a.bhh1[1024+cell];
          float go = acc[3*4+c4] + a.bih1[1536+cell]   + a.bhh1[1536+cell];
          float cp = c1s[c4*16+b16];
          float cn = sigf(gf)*cp + sigf(gi)*tanhfast(gg);
          float hn = sigf(go)*tanhfast(cn);
          c1s[c4*16+b16] = cn;
          AT_STORE(&h1_wr[bb*512 + cell], hn);
          a.h1_all[((size_t)(bb*T_ + t))*512 + cell] = f2bf(hn);
        }
      }
    }
    gbar(a.slots, a.go, genb+4);
  }
}

// ---------- host ----------

extern "C" void kernel_launch(void* const* d_in, const int* in_sizes, int n_in,
                              void* d_out, int out_size, void* d_ws, size_t ws_size,
                              hipStream_t stream){
  const float* enc   = (const float*)d_in[0];
  const int*   caps  = (const int*)d_in[1];
  const float* embW  = (const float*)d_in[2];
  const float* fc_b  = (const float*)d_in[3];
  const float* Wenc  = (const float*)d_in[4];
  const float* benc  = (const float*)d_in[5];
  const float* Wdec  = (const float*)d_in[6];
  const float* bdec  = (const float*)d_in[7];
  const float* Wfull = (const float*)d_in[8];
  const float* bfull = (const float*)d_in[9];
  const float* Wih0  = (const float*)d_in[10];
  const float* Whh0  = (const float*)d_in[11];
  const float* bih0  = (const float*)d_in[12];
  const float* bhh0  = (const float*)d_in[13];
  const float* Wih1  = (const float*)d_in[14];
  const float* Whh1  = (const float*)d_in[15];
  const float* bih1  = (const float*)d_in[16];
  const float* bhh1  = (const float*)d_in[17];
  const float* Winh  = (const float*)d_in[18];
  const float* binh  = (const float*)d_in[19];
  const float* Winc  = (const float*)d_in[20];
  const float* binc  = (const float*)d_in[21];
  float* out = (float*)d_out;

  char* wsp = (char*)d_ws;
  size_t off = 0;
  auto alloc = [&](size_t bytes)->char*{
    char* p = wsp + off;
    off += (bytes + 255) & ~(size_t)255;
    return p;
  };
  u16*   A_enc    = (u16*)  alloc((size_t)6272*512*2);
  u16*   emb_bf   = (u16*)  alloc((size_t)V_*512*2);
  u16*   WencT    = (u16*)  alloc((size_t)512*512*2);
  u16*   WdecBF   = (u16*)  alloc((size_t)512*512*2);
  float* encatt   = (float*)alloc((size_t)6272*512*4);
  u16*   encattBF = (u16*)  alloc((size_t)6272*512*2);
  float* meanb    = (float*)alloc((size_t)32*512*4);
  float* W0f      = (float*)alloc((size_t)2048*1536*4);
  float* W1f      = (float*)alloc((size_t)2048*1024*4);
  float* h0g      = (float*)alloc((size_t)65*SLABF*4);
  float* h1g      = (float*)alloc((size_t)65*SLABF*4);
  float* att2g    = (float*)alloc((size_t)65*SLABF*4);
  float* ctxg     = (float*)alloc((size_t)65*SLABF*4);
  float* c0init   = (float*)alloc(32*512*4);
  float* c1init   = (float*)alloc(32*512*4);
  u16*   h1_all   = (u16*)  alloc((size_t)2048*512*2);
  int*   syncA    = (int*)  alloc(257*4);
  if (off > ws_size) return;
  int* slots = syncA; int* go = syncA + 256;

  // setup
  hipMemsetAsync(syncA, 0, 257*4, stream);
  k_cvt_bf16<<<1568, 256, 0, stream>>>(enc, A_enc, 401408);
  k_cvt_bf16<<<8000, 256, 0, stream>>>(embW, emb_bf, 2048000);
  k_cvt_bf16<<<128, 256, 0, stream>>>(Wdec, WdecBF, 32768);
  k_wencT   <<<128, 256, 0, stream>>>(Wenc, WencT);
  k_mean    <<<32, 256, 0, stream>>>(enc, meanb);
  k_init_state<<<256, 256, 0, stream>>>(meanb, Winh, binh, Winc, binc,
                                        h0g, h1g, c0init, c1init);   // slot 0 = init
  k_fuse_w<<<4096, 256, 0, stream>>>(Wih0, Whh0, Wih1, Whh1, W0f, W1f);
  k_gemm_bf16<<<dim3(49, 4), 256, 0, stream>>>(A_enc, WencT, benc, encatt, 512);
  k_cvt_bf16<<<1568, 256, 0, stream>>>(encatt, encattBF, 401408);

  // persistent recurrence (cooperative: guarantees 256-block co-residency)
  RA ra;
  ra.enc = enc; ra.caps = caps; ra.embW = embW;
  ra.WdecBF = WdecBF; ra.bdec = bdec; ra.Wfull = Wfull; ra.bfull = bfull;
  ra.encattBF = encattBF; ra.W0f = W0f; ra.W1f = W1f;
  ra.bih0 = bih0; ra.bhh0 = bhh0; ra.bih1 = bih1; ra.bhh1 = bhh1;
  ra.h0g = h0g; ra.h1g = h1g; ra.att2g = att2g; ra.ctxg = ctxg;
  ra.c0init = c0init; ra.c1init = c1init;
  ra.h1_all = h1_all; ra.slots = slots; ra.go = go;
  void* kp[] = { &ra };
  hipLaunchCooperativeKernel((const void*)k_recur, dim3(256), dim3(512), kp, 0, stream);

  // deferred tied-weight projection: out[2048][32000] = h1_all @ emb_W^T + fc_b
  k_gemm_bf16<<<dim3(16, 250), 256, 0, stream>>>(h1_all, emb_bf, fc_b, out, V_);
}

// Round 8
// 2446.639 us; speedup vs baseline: 6.9244x; 2.1801x over previous
//
#include <hip/hip_runtime.h>

typedef unsigned short u16;
typedef __attribute__((ext_vector_type(4))) float f32x4;
typedef __attribute__((ext_vector_type(2))) float f32x2;
typedef __attribute__((ext_vector_type(8))) short short8;

#define B_ 32
#define P_ 196
#define T_ 64
#define V_ 32000
#define SLABF 17408   // 68 KB slab stride in floats (64KB data + guard)

// Cross-block exchange protocol (proven rounds 4-7):
//   producers: relaxed device-scope atomic stores (write-through to MALL).
//   consumers: plain cached loads on t-indexed slabs (fresh addresses per step
//   -> no stale line can exist; miss fills L2 so XCD blocks dedup the read).
#define AT_LOAD(p)     __hip_atomic_load((p), __ATOMIC_RELAXED, __HIP_MEMORY_SCOPE_AGENT)
#define AT_STORE(p,v)  __hip_atomic_store((p), (v), __ATOMIC_RELAXED, __HIP_MEMORY_SCOPE_AGENT)

__device__ __forceinline__ u16 f2bf(float x){
  unsigned int u = __float_as_uint(x);
  u += 0x7FFFu + ((u >> 16) & 1u);
  return (u16)(u >> 16);
}
__device__ __forceinline__ float bf2f(u16 x){
  return __uint_as_float(((unsigned int)x) << 16);
}
__device__ __forceinline__ float sigf(float x){ return 1.0f/(1.0f + __expf(-x)); }
__device__ __forceinline__ float tanhfast(float x){
  float e = __expf(-2.0f*fabsf(x));
  float t = (1.0f - e)/(1.0f + e);
  return x >= 0.0f ? t : -t;
}

// ---------- setup kernels ----------

__global__ __launch_bounds__(256) void k_cvt_bf16(const float* __restrict__ s,
                                                  u16* __restrict__ d, int n8){
  int i = blockIdx.x*256 + threadIdx.x;
  if (i >= n8) return;
  const f32x4* sp = (const f32x4*)(s + (size_t)i*8);
  f32x4 a = sp[0], b = sp[1];
  short8 v;
#pragma unroll
  for (int j=0;j<4;++j){ v[j] = (short)f2bf(a[j]); v[4+j] = (short)f2bf(b[j]); }
  *(short8*)(d + (size_t)i*8) = v;
}

__global__ __launch_bounds__(256) void k_wencT(const float* __restrict__ W, u16* __restrict__ WT){
  int tid = threadIdx.x;
  int kc = tid & 63, a = blockIdx.x*4 + (tid >> 6);
  short8 v;
#pragma unroll
  for (int j=0;j<8;++j) v[j] = (short)f2bf(W[(kc*8+j)*512 + a]);
  *(short8*)(WT + a*512 + kc*8) = v;
}

__global__ __launch_bounds__(256) void k_mean(const float* __restrict__ enc, float* __restrict__ mean){
  int b = blockIdx.x, tid = threadIdx.x;
  f32x2 acc; acc.x = 0.f; acc.y = 0.f;
  for (int p=0;p<P_;++p){
    f32x2 v = *(const f32x2*)(enc + ((size_t)(b*P_+p))*512 + tid*2);
    acc.x += v.x; acc.y += v.y;
  }
  acc.x *= (1.0f/196.0f); acc.y *= (1.0f/196.0f);
  *(f32x2*)(mean + b*512 + tid*2) = acc;
}

__global__ __launch_bounds__(256) void k_init_state(const float* __restrict__ mean,
    const float* __restrict__ Wh, const float* __restrict__ bh,
    const float* __restrict__ Wc, const float* __restrict__ bc,
    float* __restrict__ h0, float* __restrict__ h1,
    float* __restrict__ c0, float* __restrict__ c1){
  int bid = blockIdx.x;
  int which = bid >> 7, r = (bid >> 2) & 31, jg = bid & 3;
  const float* W = which ? Wc : Wh;
  const float* bb = which ? bc : bh;
  __shared__ float m[512];
  for (int i=threadIdx.x; i<512; i+=256) m[i] = mean[r*512 + i];
  __syncthreads();
  int j = jg*256 + threadIdx.x;
  float acc = bb[j];
  for (int e=0;e<512;++e) acc += m[e]*W[e*1024 + j];
  int l = r >> 4;
  int bb2 = ((r & 15) << 1) | (j >> 9);
  int hh = j & 511;
  float* dst = which ? (l ? c1 : c0) : (l ? h1 : h0);
  dst[bb2*512 + hh] = acc;
}

// fused LSTM weights: W0f[2048][1536] = [Wih0 | Whh0], W1f[2048][1024] = [Wih1 | Whh1]
__global__ __launch_bounds__(256) void k_fuse_w(const float* __restrict__ Wih0,
    const float* __restrict__ Whh0, const float* __restrict__ Wih1,
    const float* __restrict__ Whh1, float* __restrict__ W0f, float* __restrict__ W1f){
  int r = blockIdx.x, tid = threadIdx.x;
  if (r < 2048){
    for (int k=tid; k<1536; k+=256)
      W0f[(size_t)r*1536+k] = (k<1024) ? Wih0[(size_t)r*1024+k] : Whh0[(size_t)r*512 + (k-1024)];
  } else {
    int r1 = r - 2048;
    for (int k=tid; k<1024; k+=256)
      W1f[(size_t)r1*1024+k] = (k<512) ? Wih1[(size_t)r1*512+k] : Whh1[(size_t)r1*512 + (k-512)];
  }
}

// ---------- bf16 GEMM (LDS pad 40 u16): C[M][N] = A[M][512]*Bm[N][512]^T + bias ----------
#define LDAP 40
__global__ __launch_bounds__(256) void k_gemm_bf16(
    const u16* __restrict__ A, const u16* __restrict__ Bm,
    const float* __restrict__ bias, float* __restrict__ C, int N){
  __shared__ __align__(16) u16 As[128*LDAP];
  __shared__ __align__(16) u16 Bs[128*LDAP];
  int tid = threadIdx.x, l = tid & 63, w = tid >> 6;
  int m0 = blockIdx.x * 128, n0 = blockIdx.y * 128;
  int wm = w >> 1, wn = w & 1;
  f32x4 acc[4][4];
#pragma unroll
  for (int a=0;a<4;++a)
#pragma unroll
    for (int b=0;b<4;++b) acc[a][b] = (f32x4)0.0f;
  int srow = tid >> 2, schunk = tid & 3;
  const u16* gA = A + (size_t)(m0 + srow)*512 + schunk*8;
  const u16* gB = Bm + (size_t)(n0 + srow)*512 + schunk*8;
  int lr = l & 15, lk = (l >> 4) * 8;
  for (int k0 = 0; k0 < 512; k0 += 32){
    short8 va0 = *(const short8*)(gA + k0);
    short8 va1 = *(const short8*)(gA + (size_t)64*512 + k0);
    short8 vb0 = *(const short8*)(gB + k0);
    short8 vb1 = *(const short8*)(gB + (size_t)64*512 + k0);
    __syncthreads();
    *(short8*)(As + srow*LDAP + schunk*8) = va0;
    *(short8*)(As + (64+srow)*LDAP + schunk*8) = va1;
    *(short8*)(Bs + srow*LDAP + schunk*8) = vb0;
    *(short8*)(Bs + (64+srow)*LDAP + schunk*8) = vb1;
    __syncthreads();
    short8 af[4], bfv[4];
#pragma unroll
    for (int mt=0; mt<4; ++mt) af[mt]  = *(const short8*)(As + (wm*64 + mt*16 + lr)*LDAP + lk);
#pragma unroll
    for (int nt=0; nt<4; ++nt) bfv[nt] = *(const short8*)(Bs + (wn*64 + nt*16 + lr)*LDAP + lk);
#pragma unroll
    for (int mt=0; mt<4; ++mt)
#pragma unroll
      for (int nt=0; nt<4; ++nt)
        acc[mt][nt] = __builtin_amdgcn_mfma_f32_16x16x32_bf16(af[mt], bfv[nt], acc[mt][nt], 0, 0, 0);
  }
#pragma unroll
  for (int mt=0; mt<4; ++mt){
    int row = m0 + wm*64 + mt*16 + ((l >> 4) << 2);
#pragma unroll
    for (int nt=0; nt<4; ++nt){
      int col = n0 + wn*64 + nt*16 + (l & 15);
      float bv = bias[col];
#pragma unroll
      for (int j=0;j<4;++j)
        C[(size_t)(row + j)*N + col] = acc[mt][nt][j] + bv;
    }
  }
}

// ---------- persistent recurrence kernel ----------

struct RA {
  const float* enc; const int* caps; const float* embW;
  const u16* WdecBF; const float* bdec; const float* Wfull; const float* bfull;
  const u16* encattBF; const float* W0f; const float* W1f;
  const float* bih0; const float* bhh0; const float* bih1; const float* bhh1;
  float* h0g; float* h1g; float* att2g; float* ctxg;    // t-indexed slabs
  const float* c0init; const float* c1init;
  u16* h1_all; int* slots; int* go;
};

__device__ __forceinline__ void gbar(int* slots, int* go, int gen){
  __syncthreads();
  if (blockIdx.x == 0){
    int tid = threadIdx.x;
    if (tid >= 1 && tid < 256){
      while (AT_LOAD(&slots[tid]) < gen) __builtin_amdgcn_s_sleep(1);
    }
    __syncthreads();
    if (tid == 0) AT_STORE(go, gen);
  } else {
    if (threadIdx.x == 0){
      AT_STORE(&slots[blockIdx.x], gen);
      while (AT_LOAD(go) < gen) __builtin_amdgcn_s_sleep(1);
    }
    __syncthreads();
  }
  asm volatile("" ::: "memory");  // no load hoisting above the poll
}

// LSTM weights LDS-resident, swizzled: float k = ksg*32 + q*4 + e of (row,ch)
// stored at [row][ch*512 + q*64 + ksg*4 + e]. A wave's ds_read_b128 then has
// 16 distinct addresses, 2 per bank-quad (2-way = free), 4-lane broadcast.
__global__ __launch_bounds__(512) void k_recur(RA a){
  int bid = blockIdx.x, tid = threadIdx.x;
  int lane = tid & 63, wv = tid >> 6;
  __shared__ __align__(16) float w0s[12288];  // 48 KB: 8 rows x 1536
  __shared__ __align__(16) float w1s[8192];   // 32 KB: 8 rows x 1024
  __shared__ float red[2048];                 // P1: h1s|gp ; P23: att2s|gp3|alph
  __shared__ float c0s[64], c1s[64];          // [ci*32 + b]
  __shared__ float SinvS;
  __shared__ int capl[32];

  int xcd = bid & 7;
  // attention role: 4 batches per XCD (encatt/enc L2-resident), 8 col-slices
  int ab = xcd*4 + ((bid >> 3) & 3);
  int as = bid >> 5, c0col = as*64;
  // LSTM role: block owns cells bid*2, bid*2+1 for ALL 32 batches
  int bb = tid >> 4, ksg = tid & 15;    // batch 0..31, k-slice (32 floats) 0..15

  // one-time: weight rows -> LDS swizzled. local row r = g*2+ci.
  for (int idx = tid; idx < 12288; idx += 512){
    int r = idx / 1536, rem = idx - r*1536;
    int ch = rem >> 9, rem2 = rem & 511;
    int q = rem2 >> 6, rem3 = rem2 & 63;
    int ks = rem3 >> 2, e = rem3 & 3;
    int grow = (r >> 1)*512 + bid*2 + (r & 1);
    w0s[idx] = a.W0f[(size_t)grow*1536 + ch*512 + ks*32 + q*4 + e];
  }
  for (int idx = tid; idx < 8192; idx += 512){
    int r = idx >> 10, rem = idx & 1023;
    int ch = rem >> 9, rem2 = rem & 511;
    int q = rem2 >> 6, rem3 = rem2 & 63;
    int ks = rem3 >> 2, e = rem3 & 3;
    int grow = (r >> 1)*512 + bid*2 + (r & 1);
    w1s[idx] = a.W1f[(size_t)grow*1024 + ch*512 + ks*32 + q*4 + e];
  }
  if (tid < 64){
    int ci = tid >> 5, b = tid & 31, cell = bid*2 + ci;
    c0s[ci*32+b] = a.c0init[b*512 + cell];
    c1s[ci*32+b] = a.c1init[b*512 + cell];
  }
  __syncthreads();

  for (int t = 0; t < T_; ++t){
    const float* h1_rd = a.h1g + (size_t)t*SLABF;        // h1(t-1); slot0 = init
    const float* h0_rd = a.h0g + (size_t)t*SLABF;
    float*       h0_wr = a.h0g + (size_t)(t+1)*SLABF;
    float*       h1_wr = a.h1g + (size_t)(t+1)*SLABF;
    float*       at_wr = a.att2g + (size_t)t*SLABF;
    const float* at_rd = at_wr;
    float*       cx_wr = a.ctxg + (size_t)t*SLABF;
    const float* cx_rd = cx_wr;
    int genb = t*4;

    // ---- P1: att2 cols [c0col, c0col+64) for batch ab ----
    {
      float* h1s = red; float* gp = red + 512;
      h1s[tid] = h1_rd[ab*512 + tid];                 // plain cached (fresh slab)
      __syncthreads();
      int c = lane, ksx = wv;
      float accp = 0.f;
      const u16* wpd = a.WdecBF + (size_t)(ksx*64)*512 + c0col + c;
#pragma unroll 8
      for (int i=0;i<64;++i) accp = fmaf(h1s[ksx*64+i], bf2f(wpd[(size_t)i*512]), accp);
      gp[ksx*64+c] = accp;
      __syncthreads();
      if (tid < 64){
        float s = a.bdec[c0col+tid];
#pragma unroll
        for (int k=0;k<8;++k) s += gp[k*64+tid];
        AT_STORE(&at_wr[ab*512 + c0col + tid], s);
      }
    }
    gbar(a.slots, a.go, genb+1);

    // ---- P23: logits + softmax (redundant per block) + ctx col-slice ----
    {
      float* att2s = red; float* gp3 = red + 512; float* alph = red + 1024;
      att2s[tid] = at_rd[ab*512 + tid];               // plain cached
      __syncthreads();
      float a2[8], wf[8];
#pragma unroll
      for (int j=0;j<8;++j){ a2[j] = att2s[lane*8+j]; wf[j] = a.Wfull[lane*8+j]; }
      float bf0 = a.bfull[0];
      int np = (wv < 4) ? 25 : 24;
      for (int i=0;i<np;++i){
        int p = wv + i*8;
        const u16* ep = a.encattBF + ((size_t)(ab*P_ + p))*512 + lane*8;
        short8 ev = *(const short8*)ep;
        float s = 0.f;
#pragma unroll
        for (int j=0;j<8;++j)
          s += fmaxf(bf2f((u16)ev[j]) + a2[j], 0.f) * wf[j];
#pragma unroll
        for (int o=32;o>=1;o>>=1) s += __shfl_xor(s, o);
        if (lane == 0) alph[p] = __expf(s + bf0);
      }
      __syncthreads();
      if (wv == 0){
        float v = 0.f;
#pragma unroll
        for (int i=0;i<4;++i){ int p = lane + 64*i; if (p < P_) v += alph[p]; }
#pragma unroll
        for (int o=32;o>=1;o>>=1) v += __shfl_xor(v, o);
        if (lane == 0) SinvS = 1.0f / v;
      }
      int c = lane, pk = wv;
      float accp = 0.f;
      for (int i=0;i<25;++i){
        int p = pk + 8*i;
        if (p < P_) accp = fmaf(alph[p], a.enc[((size_t)(ab*P_ + p))*512 + c0col + c], accp);
      }
      gp3[pk*64+c] = accp;
      __syncthreads();
      if (tid < 64){
        float s = 0.f;
#pragma unroll
        for (int k=0;k<8;++k) s += gp3[k*64+tid];
        AT_STORE(&cx_wr[ab*512 + c0col + tid], s * SinvS);
      }
    }
    gbar(a.slots, a.go, genb+2);

    // ---- P4: LSTM layer 0 — cells bid*2..+1, all 32 batches ----
    {
      if (tid < 32) capl[tid] = a.caps[tid*T_ + t];
      __syncthreads();
      float acc[8];
#pragma unroll
      for (int r=0;r<8;++r) acc[r] = 0.f;
#pragma unroll
      for (int ch=0; ch<3; ++ch){
        const float* src;
        if (ch == 0)      src = a.embW + (size_t)capl[bb]*512 + ksg*32;
        else if (ch == 1) src = cx_rd + bb*512 + ksg*32;
        else              src = h0_rd + bb*512 + ksg*32;
        f32x4 x[8];
#pragma unroll
        for (int q=0;q<8;++q) x[q] = *(const f32x4*)(src + q*4);
        const float* wb = w0s + ch*512 + ksg*4;
#pragma unroll
        for (int q=0;q<8;++q){
          f32x4 xq = x[q];
#pragma unroll
          for (int r=0;r<8;++r){
            f32x4 w4 = *(const f32x4*)(wb + r*1536 + q*64);
            acc[r] = fmaf(xq.x,w4.x, fmaf(xq.y,w4.y, fmaf(xq.z,w4.z, fmaf(xq.w,w4.w, acc[r]))));
          }
        }
      }
#pragma unroll
      for (int r=0;r<8;++r){
        float v = acc[r];
        v += __shfl_xor(v,1); v += __shfl_xor(v,2); v += __shfl_xor(v,4); v += __shfl_xor(v,8);
        acc[r] = v;
      }
      if (ksg == 0){   // one lane per batch: finalize both cells
#pragma unroll
        for (int ci=0;ci<2;++ci){
          int cell = bid*2 + ci;
          float gi = acc[0+ci] + a.bih0[cell]        + a.bhh0[cell];
          float gf = acc[2+ci] + a.bih0[512+cell]    + a.bhh0[512+cell];
          float gg = acc[4+ci] + a.bih0[1024+cell]   + a.bhh0[1024+cell];
          float go = acc[6+ci] + a.bih0[1536+cell]   + a.bhh0[1536+cell];
          float cp = c0s[ci*32+bb];
          float cn = sigf(gf)*cp + sigf(gi)*tanhfast(gg);
          float hn = sigf(go)*tanhfast(cn);
          c0s[ci*32+bb] = cn;
          AT_STORE(&h0_wr[bb*512 + cell], hn);
        }
      }
    }
    gbar(a.slots, a.go, genb+3);

    // ---- P5: LSTM layer 1 ----
    {
      float acc[8];
#pragma unroll
      for (int r=0;r<8;++r) acc[r] = 0.f;
#pragma unroll
      for (int ch=0; ch<2; ++ch){
        const float* src = (ch == 0) ? (h0_wr + bb*512 + ksg*32)
                                     : (h1_rd + bb*512 + ksg*32);
        f32x4 x[8];
#pragma unroll
        for (int q=0;q<8;++q) x[q] = *(const f32x4*)(src + q*4);
        const float* wb = w1s + ch*512 + ksg*4;
#pragma unroll
        for (int q=0;q<8;++q){
          f32x4 xq = x[q];
#pragma unroll
          for (int r=0;r<8;++r){
            f32x4 w4 = *(const f32x4*)(wb + r*1024 + q*64);
            acc[r] = fmaf(xq.x,w4.x, fmaf(xq.y,w4.y, fmaf(xq.z,w4.z, fmaf(xq.w,w4.w, acc[r]))));
          }
        }
      }
#pragma unroll
      for (int r=0;r<8;++r){
        float v = acc[r];
        v += __shfl_xor(v,1); v += __shfl_xor(v,2); v += __shfl_xor(v,4); v += __shfl_xor(v,8);
        acc[r] = v;
      }
      if (ksg == 0){
#pragma unroll
        for (int ci=0;ci<2;++ci){
          int cell = bid*2 + ci;
          float gi = acc[0+ci] + a.bih1[cell]        + a.bhh1[cell];
          float gf = acc[2+ci] + a.bih1[512+cell]    + a.bhh1[512+cell];
          float gg = acc[4+ci] + a.bih1[1024+cell]   + a.bhh1[1024+cell];
          float go = acc[6+ci] + a.bih1[1536+cell]   + a.bhh1[1536+cell];
          float cp = c1s[ci*32+bb];
          float cn = sigf(gf)*cp + sigf(gi)*tanhfast(gg);
          float hn = sigf(go)*tanhfast(cn);
          c1s[ci*32+bb] = cn;
          AT_STORE(&h1_wr[bb*512 + cell], hn);
          a.h1_all[((size_t)(bb*T_ + t))*512 + cell] = f2bf(hn);
        }
      }
    }
    gbar(a.slots, a.go, genb+4);
  }
}

// ---------- host ----------

extern "C" void kernel_launch(void* const* d_in, const int* in_sizes, int n_in,
                              void* d_out, int out_size, void* d_ws, size_t ws_size,
                              hipStream_t stream){
  const float* enc   = (const float*)d_in[0];
  const int*   caps  = (const int*)d_in[1];
  const float* embW  = (const float*)d_in[2];
  const float* fc_b  = (const float*)d_in[3];
  const float* Wenc  = (const float*)d_in[4];
  const float* benc  = (const float*)d_in[5];
  const float* Wdec  = (const float*)d_in[6];
  const float* bdec  = (const float*)d_in[7];
  const float* Wfull = (const float*)d_in[8];
  const float* bfull = (const float*)d_in[9];
  const float* Wih0  = (const float*)d_in[10];
  const float* Whh0  = (const float*)d_in[11];
  const float* bih0  = (const float*)d_in[12];
  const float* bhh0  = (const float*)d_in[13];
  const float* Wih1  = (const float*)d_in[14];
  const float* Whh1  = (const float*)d_in[15];
  const float* bih1  = (const float*)d_in[16];
  const float* bhh1  = (const float*)d_in[17];
  const float* Winh  = (const float*)d_in[18];
  const float* binh  = (const float*)d_in[19];
  const float* Winc  = (const float*)d_in[20];
  const float* binc  = (const float*)d_in[21];
  float* out = (float*)d_out;

  char* wsp = (char*)d_ws;
  size_t off = 0;
  auto alloc = [&](size_t bytes)->char*{
    char* p = wsp + off;
    off += (bytes + 255) & ~(size_t)255;
    return p;
  };
  u16*   A_enc    = (u16*)  alloc((size_t)6272*512*2);
  u16*   emb_bf   = (u16*)  alloc((size_t)V_*512*2);
  u16*   WencT    = (u16*)  alloc((size_t)512*512*2);
  u16*   WdecBF   = (u16*)  alloc((size_t)512*512*2);
  float* encatt   = (float*)alloc((size_t)6272*512*4);
  u16*   encattBF = (u16*)  alloc((size_t)6272*512*2);
  float* meanb    = (float*)alloc((size_t)32*512*4);
  float* W0f      = (float*)alloc((size_t)2048*1536*4);
  float* W1f      = (float*)alloc((size_t)2048*1024*4);
  float* h0g      = (float*)alloc((size_t)65*SLABF*4);
  float* h1g      = (float*)alloc((size_t)65*SLABF*4);
  float* att2g    = (float*)alloc((size_t)65*SLABF*4);
  float* ctxg     = (float*)alloc((size_t)65*SLABF*4);
  float* c0init   = (float*)alloc(32*512*4);
  float* c1init   = (float*)alloc(32*512*4);
  u16*   h1_all   = (u16*)  alloc((size_t)2048*512*2);
  int*   syncA    = (int*)  alloc(257*4);
  if (off > ws_size) return;
  int* slots = syncA; int* go = syncA + 256;

  // setup
  hipMemsetAsync(syncA, 0, 257*4, stream);
  k_cvt_bf16<<<1568, 256, 0, stream>>>(enc, A_enc, 401408);
  k_cvt_bf16<<<8000, 256, 0, stream>>>(embW, emb_bf, 2048000);
  k_cvt_bf16<<<128, 256, 0, stream>>>(Wdec, WdecBF, 32768);
  k_wencT   <<<128, 256, 0, stream>>>(Wenc, WencT);
  k_mean    <<<32, 256, 0, stream>>>(enc, meanb);
  k_init_state<<<256, 256, 0, stream>>>(meanb, Winh, binh, Winc, binc,
                                        h0g, h1g, c0init, c1init);   // slot 0 = init
  k_fuse_w<<<4096, 256, 0, stream>>>(Wih0, Whh0, Wih1, Whh1, W0f, W1f);
  k_gemm_bf16<<<dim3(49, 4), 256, 0, stream>>>(A_enc, WencT, benc, encatt, 512);
  k_cvt_bf16<<<1568, 256, 0, stream>>>(encatt, encattBF, 401408);

  // persistent recurrence (cooperative: guarantees 256-block co-residency)
  RA ra;
  ra.enc = enc; ra.caps = caps; ra.embW = embW;
  ra.WdecBF = WdecBF; ra.bdec = bdec; ra.Wfull = Wfull; ra.bfull = bfull;
  ra.encattBF = encattBF; ra.W0f = W0f; ra.W1f = W1f;
  ra.bih0 = bih0; ra.bhh0 = bhh0; ra.bih1 = bih1; ra.bhh1 = bhh1;
  ra.h0g = h0g; ra.h1g = h1g; ra.att2g = att2g; ra.ctxg = ctxg;
  ra.c0init = c0init; ra.c1init = c1init;
  ra.h1_all = h1_all; ra.slots = slots; ra.go = go;
  void* kp[] = { &ra };
  hipLaunchCooperativeKernel((const void*)k_recur, dim3(256), dim3(512), kp, 0, stream);

  // deferred tied-weight projection: out[2048][32000] = h1_all @ emb_W^T + fc_b
  k_gemm_bf16<<<dim3(16, 250), 256, 0, stream>>>(h1_all, emb_bf, fc_b, out, V_);
}